// Round 16
// baseline (579.030 us; speedup 1.0000x reference)
//
#include <hip/hip_runtime.h>
#include <math.h>

#define Bsz 2048

using bf16x8 = __attribute__((ext_vector_type(8))) short;
using f32x4  = __attribute__((ext_vector_type(4))) float;

__device__ __forceinline__ float fast_tanh(float x){
    float e = __expf(2.0f * x);
    return 1.0f - 2.0f / (e + 1.0f);
}
__device__ __forceinline__ float fast_sigmoid(float x){
    return 1.0f / (1.0f + __expf(-x));
}
__device__ __forceinline__ unsigned short f2b(float f){
    union { float f; unsigned u; } v; v.f = f;
    unsigned r = v.u + 0x7FFFu + ((v.u >> 16) & 1u);
    return (unsigned short)(r >> 16);
}
__device__ __forceinline__ float b2f(unsigned short s){
    union { unsigned u; float f; } v; v.u = ((unsigned)s) << 16;
    return v.f;
}

__device__ __forceinline__ float stage_t(int sidx){
    int i  = sidx >> 2, st = sidx & 3;
    float t = 10.0f - 0.5f * (float)i;
    if (st == 1 || st == 2) t -= 0.25f;
    else if (st == 3)       t -= 0.5f;
    return t;
}

// ===== weight prep ==========================================================
__global__ void k_prep(const float* __restrict__ c1w, const float* __restrict__ c2w,
                       const float* __restrict__ t0w, const float* __restrict__ t1w,
                       const float* __restrict__ elw, const float* __restrict__ dlw,
                       const float* __restrict__ elb, const float* __restrict__ dlb,
                       const float* __restrict__ t2w,
                       unsigned short* __restrict__ wc1, unsigned short* __restrict__ wc2,
                       unsigned short* __restrict__ wt0, unsigned short* __restrict__ wt1,
                       unsigned short* __restrict__ t2wPk,
                       unsigned short* __restrict__ elwT, unsigned short* __restrict__ dlwT,
                       float* __restrict__ dlbT, float* __restrict__ z1, int full){
    int gsz = gridDim.x * 256;
    for (int i = blockIdx.x*256 + threadIdx.x; i < 9216; i += gsz){
        int ci = i & 31, co = (i >> 5) & 31, s = i >> 10;
        wc1[i] = f2b(c1w[(co*32 + ci)*9 + s]);
        wc2[i] = f2b(c2w[(co*32 + ci)*9 + s]);
        wt0[i] = f2b(t0w[(ci*32 + co)*9 + (8 - s)]);
        wt1[i] = f2b(t1w[(ci*32 + co)*9 + (8 - s)]);
    }
    if (!full) return;
    for (int i = blockIdx.x*256 + threadIdx.x; i < 288; i += gsz){
        int tap = i >> 5, ci = i & 31;
        int r = tap / 3, s = tap - r*3;
        t2wPk[i] = f2b(t2w[ci*9 + (2-r)*3 + (2-s)]);
    }
    for (int i = blockIdx.x*256 + threadIdx.x; i < 32768; i += gsz)
        z1[i] = elb[i & 15];
    for (int i = blockIdx.x*256 + threadIdx.x; i < 15488; i += gsz){
        int pos = i >> 5, ci = i & 31;
        dlbT[i] = dlb[ci*484 + pos];
    }
    for (int i = blockIdx.x*256 + threadIdx.x; i < 247808; i += gsz){
        int l = i / 15488, f2 = i - l*15488;
        int pos = f2 >> 5, ci = f2 & 31;
        elwT[i] = f2b(elw[(ci*484 + pos)*16 + l]);
    }
    for (int i = blockIdx.x*256 + threadIdx.x; i < 247808; i += gsz){
        int f2 = i >> 4, l = i & 15;
        int pos = f2 >> 5, ci = f2 & 31;
        dlwT[i] = f2b(dlw[l*15488 + ci*484 + pos]);
    }
}

// ===== fused conv0 (1->32, VALU, ->LDS) + conv1 (MFMA, LDS->A1 global) =====
__global__ void __launch_bounds__(256)
k_enc01(const float* __restrict__ x, const float* __restrict__ c0w,
        const float* __restrict__ c0b, const unsigned short* __restrict__ wc1,
        const float* __restrict__ c1b, unsigned short* __restrict__ A1,
        int cb){
    __shared__ __align__(16) unsigned short A0L[676*36];
    __shared__ float X[784];
    const int tid = threadIdx.x, b = blockIdx.x;
    const float* xin = x + (size_t)(cb + b)*784;

    for (int i = tid; i < 784; i += 256) X[i] = xin[i];
    __syncthreads();

    for (int pos = tid; pos < 676; pos += 256){
        int y = pos / 26, xx = pos - y*26;
        float v[9];
#pragma unroll
        for (int r = 0; r < 3; r++)
#pragma unroll
            for (int s = 0; s < 3; s++)
                v[r*3+s] = X[(y+r)*28 + xx + s];
        float acc[32];
#pragma unroll
        for (int co = 0; co < 32; co++) acc[co] = c0b[co];
#pragma unroll
        for (int k = 0; k < 9; k++)
#pragma unroll
            for (int co = 0; co < 32; co++)
                acc[co] += v[k] * c0w[co*9 + k];
        unsigned short* ob = A0L + pos*36;
#pragma unroll
        for (int g = 0; g < 8; g++){
            ushort4 o;
            o.x = f2b(fast_tanh(acc[g*4+0])); o.y = f2b(fast_tanh(acc[g*4+1]));
            o.z = f2b(fast_tanh(acc[g*4+2])); o.w = f2b(fast_tanh(acc[g*4+3]));
            *(ushort4*)(ob + g*4) = o;
        }
    }
    __syncthreads();

    const int wave = tid >> 6, lane = tid & 63;
    const int q = lane >> 4, nn = lane & 15;
    bf16x8 af[2][9];
#pragma unroll
    for (int mt = 0; mt < 2; mt++)
#pragma unroll
        for (int s = 0; s < 9; s++)
            af[mt][s] = *(const bf16x8*)(wc1 + s*1024 + (mt*16 + nn)*32 + q*8);
    float4 bc0 = *(const float4*)(c1b + q*4);
    float4 bc1 = *(const float4*)(c1b + 16 + q*4);
    unsigned short* outb = A1 + (size_t)b*25088;

    for (int t = wave; t < 36; t += 4){
        int pos = t*16 + nn;
        int oy = pos / 24, ox = pos - oy*24;
        const unsigned short* ib = A0L + (oy*26 + ox)*36 + q*8;
        f32x4 acc0 = {0.f,0.f,0.f,0.f}, acc1 = {0.f,0.f,0.f,0.f};
#pragma unroll
        for (int r = 0; r < 3; r++){
            bf16x8 b0 = *(const bf16x8*)(ib + (r*26 + 0)*36);
            bf16x8 b1 = *(const bf16x8*)(ib + (r*26 + 1)*36);
            bf16x8 b2 = *(const bf16x8*)(ib + (r*26 + 2)*36);
            acc0 = __builtin_amdgcn_mfma_f32_16x16x32_bf16(af[0][r*3+0], b0, acc0, 0,0,0);
            acc1 = __builtin_amdgcn_mfma_f32_16x16x32_bf16(af[1][r*3+0], b0, acc1, 0,0,0);
            acc0 = __builtin_amdgcn_mfma_f32_16x16x32_bf16(af[0][r*3+1], b1, acc0, 0,0,0);
            acc1 = __builtin_amdgcn_mfma_f32_16x16x32_bf16(af[1][r*3+1], b1, acc1, 0,0,0);
            acc0 = __builtin_amdgcn_mfma_f32_16x16x32_bf16(af[0][r*3+2], b2, acc0, 0,0,0);
            acc1 = __builtin_amdgcn_mfma_f32_16x16x32_bf16(af[1][r*3+2], b2, acc1, 0,0,0);
        }
        int opix = oy*24 + ox;
        ushort4 o0, o1;
        o0.x = f2b(fast_tanh(acc0[0] + bc0.x)); o0.y = f2b(fast_tanh(acc0[1] + bc0.y));
        o0.z = f2b(fast_tanh(acc0[2] + bc0.z)); o0.w = f2b(fast_tanh(acc0[3] + bc0.w));
        o1.x = f2b(fast_tanh(acc1[0] + bc1.x)); o1.y = f2b(fast_tanh(acc1[1] + bc1.y));
        o1.z = f2b(fast_tanh(acc1[2] + bc1.z)); o1.w = f2b(fast_tanh(acc1[3] + bc1.w));
        *(ushort4*)(outb + opix*32 + q*4)      = o0;
        *(ushort4*)(outb + opix*32 + 16 + q*4) = o1;
    }
}

// ===== MFMA conv layer global->global (conv2) ==============================
template<int IL, int OL, int OW, int OOFF, int INS, int OUTS>
__global__ void __launch_bounds__(256)
k_convM(const unsigned short* __restrict__ in, const unsigned short* __restrict__ wg,
        const float* __restrict__ bias, unsigned short* __restrict__ out, int CH){
    constexpr int N  = OL * OL;
    constexpr int NT = (N + 15) / 16;
    const int tid = threadIdx.x;
    const int wave = tid >> 6, lane = tid & 63;
    const int q = lane >> 4, nn = lane & 15;
    const int nw = gridDim.x * 4;

    bf16x8 af[2][9];
#pragma unroll
    for (int mt = 0; mt < 2; mt++)
#pragma unroll
        for (int s = 0; s < 9; s++)
            af[mt][s] = *(const bf16x8*)(wg + s*1024 + (mt*16 + nn)*32 + q*8);
    float4 bc0 = *(const float4*)(bias + q*4);
    float4 bc1 = *(const float4*)(bias + 16 + q*4);

    for (int t = blockIdx.x*4 + wave; t < CH*NT; t += nw){
        int img = t / NT, tt = t - img*NT;
        const unsigned short* inb = in + (size_t)img * INS;
        unsigned short* outb = out + (size_t)img * OUTS;
        int pos = tt*16 + nn;
        int pc  = pos < N ? pos : N - 1;
        int oy = pc / OL, ox = pc - oy*OL;
        const unsigned short* ib = inb + (oy*IL + ox)*32 + q*8;
        f32x4 acc0 = {0.f,0.f,0.f,0.f}, acc1 = {0.f,0.f,0.f,0.f};
#pragma unroll
        for (int r = 0; r < 3; r++){
            bf16x8 b0 = *(const bf16x8*)(ib + (r*IL + 0)*32);
            bf16x8 b1 = *(const bf16x8*)(ib + (r*IL + 1)*32);
            bf16x8 b2 = *(const bf16x8*)(ib + (r*IL + 2)*32);
            acc0 = __builtin_amdgcn_mfma_f32_16x16x32_bf16(af[0][r*3+0], b0, acc0, 0,0,0);
            acc1 = __builtin_amdgcn_mfma_f32_16x16x32_bf16(af[1][r*3+0], b0, acc1, 0,0,0);
            acc0 = __builtin_amdgcn_mfma_f32_16x16x32_bf16(af[0][r*3+1], b1, acc0, 0,0,0);
            acc1 = __builtin_amdgcn_mfma_f32_16x16x32_bf16(af[1][r*3+1], b1, acc1, 0,0,0);
            acc0 = __builtin_amdgcn_mfma_f32_16x16x32_bf16(af[0][r*3+2], b2, acc0, 0,0,0);
            acc1 = __builtin_amdgcn_mfma_f32_16x16x32_bf16(af[1][r*3+2], b2, acc1, 0,0,0);
        }
        if (pos < N){
            int opix = oy*OW + ox + OOFF;
            ushort4 o0, o1;
            o0.x = f2b(fast_tanh(acc0[0] + bc0.x)); o0.y = f2b(fast_tanh(acc0[1] + bc0.y));
            o0.z = f2b(fast_tanh(acc0[2] + bc0.z)); o0.w = f2b(fast_tanh(acc0[3] + bc0.w));
            o1.x = f2b(fast_tanh(acc1[0] + bc1.x)); o1.y = f2b(fast_tanh(acc1[1] + bc1.y));
            o1.z = f2b(fast_tanh(acc1[2] + bc1.z)); o1.w = f2b(fast_tanh(acc1[3] + bc1.w));
            *(ushort4*)(outb + opix*32 + q*4)      = o0;
            *(ushort4*)(outb + opix*32 + 16 + q*4) = o1;
        }
    }
}

// ===== encoder GEMM (A2 in Y, stride 15488) ================================
__global__ void __launch_bounds__(256)
k_encg(const unsigned short* __restrict__ A2, const unsigned short* __restrict__ elwT,
       float* __restrict__ z1, int cb, int CH){
    int wave = threadIdx.x >> 6, lane = threadIdx.x & 63;
    int q = lane >> 4, nn = lane & 15;
    int imgb = blockIdx.x*16;
    const unsigned short* ap = A2 + (size_t)(imgb + nn)*15488 + q*8;
    const unsigned short* bp = elwT + (size_t)nn*15488 + q*8;
    f32x4 acc = {0.f,0.f,0.f,0.f};
    int s0 = blockIdx.y*121;
#pragma unroll 2
    for (int s = s0 + wave; s < s0 + 121; s += 4){
        bf16x8 a = *(const bf16x8*)(ap + s*32);
        bf16x8 b = *(const bf16x8*)(bp + s*32);
        acc = __builtin_amdgcn_mfma_f32_16x16x32_bf16(a, b, acc, 0,0,0);
    }
    float* zp = z1 + (size_t)(cb + imgb)*16;
#pragma unroll
    for (int i = 0; i < 4; i++)
        atomicAdd(zp + (q*4 + i)*16 + nn, acc[i]);
}

// ===== decoder as batch GEMM ==============================================
__global__ void __launch_bounds__(256)
k_decgM(const float* __restrict__ z1, const unsigned short* __restrict__ dlwT,
        const float* __restrict__ dlbT, unsigned short* __restrict__ D0c, int cb){
    __shared__ float zb[16*17];
    const int tid = threadIdx.x;
    const int wave = tid >> 6, lane = tid & 63;
    const int q = lane >> 4, n = lane & 15;
    const int imgb = blockIdx.y*16;
    zb[(tid >> 4)*17 + (tid & 15)] = z1[(size_t)(cb + imgb + (tid >> 4))*16 + (tid & 15)];
    __syncthreads();

    bf16x8 zf;
    if (q < 2){
        unsigned short tmp[8];
#pragma unroll
        for (int j = 0; j < 8; j++) tmp[j] = f2b(zb[n*17 + q*8 + j]);
        zf = *(bf16x8*)tmp;
    } else {
        bf16x8 zz = {0,0,0,0,0,0,0,0}; zf = zz;
    }

#pragma unroll
    for (int ii = 0; ii < 4; ii++){
        int mt = blockIdx.x*16 + wave*4 + ii;
        if (mt >= 968) break;
        int mb = mt*16;
        bf16x8 afr;
        if (q < 2) afr = *(const bf16x8*)(dlwT + (size_t)(mb + n)*16 + q*8);
        else { bf16x8 zz = {0,0,0,0,0,0,0,0}; afr = zz; }
        f32x4 acc = {0.f,0.f,0.f,0.f};
        acc = __builtin_amdgcn_mfma_f32_16x16x32_bf16(afr, zf, acc, 0,0,0);
        float4 bias = *(const float4*)(dlbT + mb + q*4);
        ushort4 o;
        o.x = f2b(fast_tanh(acc[0] + bias.x));
        o.y = f2b(fast_tanh(acc[1] + bias.y));
        o.z = f2b(fast_tanh(acc[2] + bias.z));
        o.w = f2b(fast_tanh(acc[3] + bias.w));
        *(ushort4*)(D0c + (size_t)(imgb + n)*15488 + mb + q*4) = o;
    }
}

// ===== CNF half (device; single wave, stages [s0,s1), state in/out) ========
struct PM {
    bf16x8 Wf[4];
    bf16x8 Uf[2];
    float4 Bbf[4];
    float4 sf[4];
    float stot;
};
__device__ __forceinline__ void loadPM(const float* __restrict__ g, int lane, int q, PM& p){
    const unsigned short* gW = (const unsigned short*)g;
    const unsigned short* gU = (const unsigned short*)(g + 1024);
#pragma unroll
    for (int c = 0; c < 4; c++)
        p.Wf[c] = *(const bf16x8*)(gW + (c*64 + lane)*8);
#pragma unroll
    for (int kb = 0; kb < 2; kb++)
        p.Uf[kb] = *(const bf16x8*)(gU + (kb*64 + lane)*8);
#pragma unroll
    for (int c = 0; c < 4; c++){
        p.Bbf[c] = *(const float4*)(g + 1536 + c*16 + q*4);
        p.sf[c]  = *(const float4*)(g + 1600 + c*16 + q*4);
    }
    p.stot = g[1664];
}

__device__ __forceinline__ void cnf_half(const float* __restrict__ zin,
                                         const float* __restrict__ lpin,
                                         float* __restrict__ zout,
                                         float* __restrict__ lpout,
                                         float* __restrict__ part,
                                         const float* __restrict__ hyp,
                                         int bid, int s0, int s1, int finalize,
                                         unsigned short* zsb, unsigned short* hhT){
    const int lane = threadIdx.x;
    const int q = lane >> 4, d = lane & 15;
    const float dt = -0.5f;

    float z[4], zacc[4], lacc[4], lp[4];
#pragma unroll
    for (int i = 0; i < 4; i++){
        z[i] = zin[(size_t)(bid*16 + q*4 + i)*16 + d];
        lp[i] = lpin ? lpin[bid*16 + q*4 + i] : 0.f;
        zacc[i] = 0.f; lacc[i] = 0.f;
        zsb[(q*4 + i)*24 + d] = f2b(z[i]);
    }
    PM pm0, pm1;
    loadPM(hyp + (size_t)s0*2048, lane, q, pm0);

#pragma unroll 2
    for (int sidx = s0; sidx < s1; sidx++){
        PM& cur = (sidx & 1) ? pm1 : pm0;
        PM& nxt = (sidx & 1) ? pm0 : pm1;
        if (sidx + 1 < 80) loadPM(hyp + (size_t)(sidx + 1)*2048, lane, q, nxt);

        bf16x8 zb;
        if (q < 2) zb = *(const bf16x8*)(zsb + d*24 + q*8);
        else { bf16x8 zz2 = {0,0,0,0,0,0,0,0}; zb = zz2; }

        f32x4 h0 = {0,0,0,0}, h1 = {0,0,0,0}, h2 = {0,0,0,0}, h3 = {0,0,0,0};
        h0 = __builtin_amdgcn_mfma_f32_16x16x32_bf16(cur.Wf[0], zb, h0, 0,0,0);
        h1 = __builtin_amdgcn_mfma_f32_16x16x32_bf16(cur.Wf[1], zb, h1, 0,0,0);
        h2 = __builtin_amdgcn_mfma_f32_16x16x32_bf16(cur.Wf[2], zb, h2, 0,0,0);
        h3 = __builtin_amdgcn_mfma_f32_16x16x32_bf16(cur.Wf[3], zb, h3, 0,0,0);

        float partial = 0.f;
        f32x4 hc[4] = {h0, h1, h2, h3};
#pragma unroll
        for (int c = 0; c < 4; c++){
            ushort4 o;
            float t0 = fast_tanh(hc[c][0] + cur.Bbf[c].x);
            float t1 = fast_tanh(hc[c][1] + cur.Bbf[c].y);
            float t2 = fast_tanh(hc[c][2] + cur.Bbf[c].z);
            float t3 = fast_tanh(hc[c][3] + cur.Bbf[c].w);
            partial += t0*t0*cur.sf[c].x + t1*t1*cur.sf[c].y
                     + t2*t2*cur.sf[c].z + t3*t3*cur.sf[c].w;
            o.x = f2b(t0); o.y = f2b(t1); o.z = f2b(t2); o.w = f2b(t3);
            *(ushort4*)(hhT + d*72 + c*16 + q*4) = o;
        }
        partial += __shfl_xor(partial, 16);
        partial += __shfl_xor(partial, 32);
        float trFull = (cur.stot - partial) * (1.f/64.f);

        bf16x8 a20 = *(const bf16x8*)(hhT + d*72 + q*8);
        bf16x8 a21 = *(const bf16x8*)(hhT + d*72 + 32 + q*8);
        f32x4 dzac = {0,0,0,0};
        dzac = __builtin_amdgcn_mfma_f32_16x16x32_bf16(a20, cur.Uf[0], dzac, 0,0,0);
        dzac = __builtin_amdgcn_mfma_f32_16x16x32_bf16(a21, cur.Uf[1], dzac, 0,0,0);

        int st = sidx & 3;
        float wgt = (st == 0 || st == 3) ? 1.f : 2.f;
#pragma unroll
        for (int i = 0; i < 4; i++){
            float dz = dzac[i] * (1.f/64.f);
            float dl = -__shfl(trFull, q*4 + i);
            zacc[i] += wgt * dz;
            lacc[i] += wgt * dl;
            float zsv;
            if (st < 3){
                float aa = (st == 2) ? 1.0f : 0.5f;
                zsv = z[i] + aa * dt * dz;
            } else {
                z[i]  += (dt/6.f) * zacc[i];
                lp[i] += (dt/6.f) * lacc[i];
                zsv = z[i];
                zacc[i] = 0.f; lacc[i] = 0.f;
            }
            zsb[(q*4 + i)*24 + d] = f2b(zsv);
        }
    }
    if (!finalize){
#pragma unroll
        for (int i = 0; i < 4; i++){
            zout[(size_t)(bid*16 + q*4 + i)*16 + d] = z[i];
            if (d == 0) lpout[bid*16 + q*4 + i] = lp[i];
        }
        return;
    }
    float sq[4];
#pragma unroll
    for (int i = 0; i < 4; i++) sq[i] = z[i]*z[i];
#pragma unroll
    for (int off = 1; off < 16; off <<= 1){
#pragma unroll
        for (int i = 0; i < 4; i++) sq[i] += __shfl_xor(sq[i], off, 16);
    }
    if (d == 0){
#pragma unroll
        for (int i = 0; i < 4; i++){
            float logp = -0.5f * (16.f*1.8378770664093453f
                                 + 16.f*(-2.302585092994046f) + sq[i]*10.f);
            part[bid*16 + q*4 + i] = logp - lp[i];
        }
    }
}

// ===== convT0 + CNF first half (CNF blocks first) ==========================
__global__ void __launch_bounds__(256)
k_dect0c(const unsigned short* __restrict__ D0c, const unsigned short* __restrict__ wt0,
         const float* __restrict__ t0b, unsigned short* __restrict__ D1,
         const float* __restrict__ z1, const float* __restrict__ hyp,
         float* __restrict__ zmid, float* __restrict__ lpmid, int nCnf){
    __shared__ __align__(16) unsigned short D0L[676*36];
    __shared__ __align__(16) unsigned short zsbS[16*24];
    __shared__ __align__(16) unsigned short hhTS[16*72];
    const int tid = threadIdx.x;

    if (blockIdx.x < nCnf){
        if (tid >= 64) return;
        cnf_half(z1, nullptr, zmid, lpmid, nullptr, hyp,
                 blockIdx.x, 0, 40, 0, zsbS, hhTS);
        return;
    }
    const int b = blockIdx.x - nCnf;
    unsigned short* d1b = D1 + (size_t)b*25088;
    {
        uint4 zq = {0,0,0,0};
        for (int p = tid; p < 676; p += 256){
            int y = p / 26, xx = p - y*26;
            if (y < 2 || y >= 24 || xx < 2 || xx >= 24){
                uint4* pt = (uint4*)(D0L + p*36);
                pt[0] = zq; pt[1] = zq; pt[2] = zq; pt[3] = zq;
            }
        }
        for (int p = tid; p < 784; p += 256){
            int y = p / 28, xx = p - y*28;
            if (y < 2 || y >= 26 || xx < 2 || xx >= 26){
                uint4* pt = (uint4*)(d1b + p*32);
                pt[0] = zq; pt[1] = zq; pt[2] = zq; pt[3] = zq;
            }
        }
    }
    {
        const uint4* src = (const uint4*)(D0c + (size_t)b*15488);
        for (int c = tid; c < 1936; c += 256){
            uint4 v = src[c];
            int pos = c >> 2, p8 = (c & 3)*8;
            int y = pos / 22, xx = pos - y*22;
            *(uint4*)(D0L + ((y+2)*26 + xx + 2)*36 + p8) = v;
        }
    }
    __syncthreads();

    const int wave = tid >> 6, lane = tid & 63;
    const int q = lane >> 4, nn = lane & 15;
    bf16x8 af[2][9];
#pragma unroll
    for (int mt = 0; mt < 2; mt++)
#pragma unroll
        for (int s = 0; s < 9; s++)
            af[mt][s] = *(const bf16x8*)(wt0 + s*1024 + (mt*16 + nn)*32 + q*8);
    float4 bc0 = *(const float4*)(t0b + q*4);
    float4 bc1 = *(const float4*)(t0b + 16 + q*4);

    for (int t = wave; t < 36; t += 4){
        int pos = t*16 + nn;
        int oy = pos / 24, ox = pos - oy*24;
        const unsigned short* ib = D0L + (oy*26 + ox)*36 + q*8;
        f32x4 acc0 = {0.f,0.f,0.f,0.f}, acc1 = {0.f,0.f,0.f,0.f};
#pragma unroll
        for (int r = 0; r < 3; r++){
            bf16x8 b0 = *(const bf16x8*)(ib + (r*26 + 0)*36);
            bf16x8 b1 = *(const bf16x8*)(ib + (r*26 + 1)*36);
            bf16x8 b2 = *(const bf16x8*)(ib + (r*26 + 2)*36);
            acc0 = __builtin_amdgcn_mfma_f32_16x16x32_bf16(af[0][r*3+0], b0, acc0, 0,0,0);
            acc1 = __builtin_amdgcn_mfma_f32_16x16x32_bf16(af[1][r*3+0], b0, acc1, 0,0,0);
            acc0 = __builtin_amdgcn_mfma_f32_16x16x32_bf16(af[0][r*3+1], b1, acc0, 0,0,0);
            acc1 = __builtin_amdgcn_mfma_f32_16x16x32_bf16(af[1][r*3+1], b1, acc1, 0,0,0);
            acc0 = __builtin_amdgcn_mfma_f32_16x16x32_bf16(af[0][r*3+2], b2, acc0, 0,0,0);
            acc1 = __builtin_amdgcn_mfma_f32_16x16x32_bf16(af[1][r*3+2], b2, acc1, 0,0,0);
        }
        int opix = oy*28 + ox + 58;
        ushort4 o0, o1;
        o0.x = f2b(fast_tanh(acc0[0] + bc0.x)); o0.y = f2b(fast_tanh(acc0[1] + bc0.y));
        o0.z = f2b(fast_tanh(acc0[2] + bc0.z)); o0.w = f2b(fast_tanh(acc0[3] + bc0.w));
        o1.x = f2b(fast_tanh(acc1[0] + bc1.x)); o1.y = f2b(fast_tanh(acc1[1] + bc1.y));
        o1.z = f2b(fast_tanh(acc1[2] + bc1.z)); o1.w = f2b(fast_tanh(acc1[3] + bc1.w));
        *(ushort4*)(d1b + opix*32 + q*4)      = o0;
        *(ushort4*)(d1b + opix*32 + 16 + q*4) = o1;
    }
}

// ===== convT1 (-> compact 26-map LDS) + convT2 (OOB-zero) + CNF 2nd half ===
__global__ void __launch_bounds__(256)
k_dect12(const unsigned short* __restrict__ D1, const unsigned short* __restrict__ wt1,
         const float* __restrict__ t1b, const unsigned short* __restrict__ t2wPk,
         const float* __restrict__ t2b, float* __restrict__ out,
         const float* __restrict__ zmid, const float* __restrict__ lpmid,
         const float* __restrict__ hyp, float* __restrict__ part,
         int cb, int nCnf){
    __shared__ __align__(16) unsigned short D2L[676*36];   // compact 26x26, stride 36
    __shared__ __align__(16) unsigned short zsbS[16*24];
    __shared__ __align__(16) unsigned short hhTS[16*72];
    const int tid = threadIdx.x;
    if (blockIdx.x < nCnf){
        if (tid >= 64) return;
        cnf_half(zmid, lpmid, nullptr, nullptr, part, hyp,
                 blockIdx.x, 40, 80, 1, zsbS, hhTS);
        return;
    }
    const int b = blockIdx.x - nCnf;
    const unsigned short* d1b = D1 + (size_t)b*25088;
    const int wave = tid >> 6, lane = tid & 63;
    const int q = lane >> 4, nn = lane & 15;

    {   // convT1: D1 (28-map global) -> D2L compact 26-map
        bf16x8 af[2][9];
#pragma unroll
        for (int mt = 0; mt < 2; mt++)
#pragma unroll
            for (int s = 0; s < 9; s++)
                af[mt][s] = *(const bf16x8*)(wt1 + s*1024 + (mt*16 + nn)*32 + q*8);
        float4 bc0 = *(const float4*)(t1b + q*4);
        float4 bc1 = *(const float4*)(t1b + 16 + q*4);

        for (int t = wave; t < 43; t += 4){
            int pos = t*16 + nn;
            int pc  = pos < 676 ? pos : 675;
            int oy = pc / 26, ox = pc - oy*26;
            const unsigned short* ib = d1b + (oy*28 + ox)*32 + q*8;
            f32x4 acc0 = {0.f,0.f,0.f,0.f}, acc1 = {0.f,0.f,0.f,0.f};
#pragma unroll
            for (int r = 0; r < 3; r++){
                bf16x8 b0 = *(const bf16x8*)(ib + (r*28 + 0)*32);
                bf16x8 b1 = *(const bf16x8*)(ib + (r*28 + 1)*32);
                bf16x8 b2 = *(const bf16x8*)(ib + (r*28 + 2)*32);
                acc0 = __builtin_amdgcn_mfma_f32_16x16x32_bf16(af[0][r*3+0], b0, acc0, 0,0,0);
                acc1 = __builtin_amdgcn_mfma_f32_16x16x32_bf16(af[1][r*3+0], b0, acc1, 0,0,0);
                acc0 = __builtin_amdgcn_mfma_f32_16x16x32_bf16(af[0][r*3+1], b1, acc0, 0,0,0);
                acc1 = __builtin_amdgcn_mfma_f32_16x16x32_bf16(af[1][r*3+1], b1, acc1, 0,0,0);
                acc0 = __builtin_amdgcn_mfma_f32_16x16x32_bf16(af[0][r*3+2], b2, acc0, 0,0,0);
                acc1 = __builtin_amdgcn_mfma_f32_16x16x32_bf16(af[1][r*3+2], b2, acc1, 0,0,0);
            }
            if (pos < 676){
                int opix = oy*26 + ox;
                ushort4 o0, o1;
                o0.x = f2b(fast_tanh(acc0[0] + bc0.x)); o0.y = f2b(fast_tanh(acc0[1] + bc0.y));
                o0.z = f2b(fast_tanh(acc0[2] + bc0.z)); o0.w = f2b(fast_tanh(acc0[3] + bc0.w));
                o1.x = f2b(fast_tanh(acc1[0] + bc1.x)); o1.y = f2b(fast_tanh(acc1[1] + bc1.y));
                o1.z = f2b(fast_tanh(acc1[2] + bc1.z)); o1.w = f2b(fast_tanh(acc1[3] + bc1.w));
                *(ushort4*)(D2L + opix*36 + q*4)      = o0;
                *(ushort4*)(D2L + opix*36 + 16 + q*4) = o1;
            }
        }
    }
    __syncthreads();

    {   // convT2: 49 tiles x 9 MFMA, per-lane OOB zero B-frags
        bf16x8 wf[9];
#pragma unroll
        for (int tap = 0; tap < 9; tap++)
            wf[tap] = *(const bf16x8*)(t2wPk + tap*32 + q*8);
        float t2b0 = t2b[0];
        const bf16x8 zvec = {0,0,0,0,0,0,0,0};
        for (int t = wave; t < 49; t += 4){
            int p = t*16 + nn;
            int y = p / 28, xx = p - y*28;
            f32x4 acc = {0.f,0.f,0.f,0.f};
#pragma unroll
            for (int r = 0; r < 3; r++){
                int iy = y + r - 2;
                bool okY = (unsigned)iy < 26u;
#pragma unroll
                for (int s = 0; s < 3; s++){
                    int ix = xx + s - 2;
                    bool ok = okY && ((unsigned)ix < 26u);
                    bf16x8 bv = ok ? *(const bf16x8*)(D2L + (iy*26 + ix)*36 + q*8)
                                   : zvec;
                    acc = __builtin_amdgcn_mfma_f32_16x16x32_bf16(wf[r*3+s], bv, acc, 0,0,0);
                }
            }
            if (q == 0)
                out[(size_t)(cb + b)*784 + p] = acc[0] + t2b0;
        }
    }
}

// ===== hypernetwork, parallel 3-kernel path ================================
__global__ void __launch_bounds__(64)
k_hyp1(const float* __restrict__ h1w, const float* __restrict__ h1b,
       const float* __restrict__ h2w, const float* __restrict__ h2b,
       float* __restrict__ p2ws){
    __shared__ float p1l[64];
    int sidx = blockIdx.x, tid = threadIdx.x;
    float t = stage_t(sidx);
    p1l[tid] = fast_tanh(t * h1w[tid] + h1b[tid]);
    __syncthreads();
    float a0 = h2b[tid], a1 = 0.f, a2 = 0.f, a3 = 0.f;
#pragma unroll
    for (int k = 0; k < 64; k += 4){
        a0 += p1l[k]   * h2w[(k)*64   + tid];
        a1 += p1l[k+1] * h2w[(k+1)*64 + tid];
        a2 += p1l[k+2] * h2w[(k+2)*64 + tid];
        a3 += p1l[k+3] * h2w[(k+3)*64 + tid];
    }
    p2ws[sidx*64 + tid] = fast_tanh((a0 + a1) + (a2 + a3));
}

__global__ void __launch_bounds__(256)
k_hyp2(const float* __restrict__ p2ws, const float* __restrict__ h3w,
       const float* __restrict__ h3b, float* __restrict__ p3ws){
    __shared__ float p2l[64];
    int sidx = blockIdx.y, tid = threadIdx.x;
    if (tid < 64) p2l[tid] = p2ws[sidx*64 + tid];
    __syncthreads();
    int m = blockIdx.x*256 + tid;
    if (m >= 3136) return;
    const float* hp = h3w + m;
    float a0 = h3b[m], a1 = 0.f, a2 = 0.f, a3 = 0.f;
#pragma unroll
    for (int k = 0; k < 64; k += 4){
        a0 += p2l[k]   * hp[(size_t)(k)*3136];
        a1 += p2l[k+1] * hp[(size_t)(k+1)*3136];
        a2 += p2l[k+2] * hp[(size_t)(k+2)*3136];
        a3 += p2l[k+3] * hp[(size_t)(k+3)*3136];
    }
    p3ws[(size_t)sidx*3200 + m] = (a0 + a1) + (a2 + a3);
}

__global__ void __launch_bounds__(256)
k_hyp3(const float* __restrict__ p3ws, float* __restrict__ hyp){
    __shared__ float sred[64];
    int sidx = blockIdx.x, tid = threadIdx.x;
    const float* p3 = p3ws + (size_t)sidx*3200;
    float* g = hyp + (size_t)sidx*2048;
    unsigned short* gW = (unsigned short*)g;
    unsigned short* gU = (unsigned short*)(g + 1024);
    {
        int lane = tid & 63, c = tid >> 6;
        int q = lane >> 4, m = lane & 15;
        ushort4 o0 = {0,0,0,0}, o1 = {0,0,0,0};
        if (q < 2){
            const float* wp = p3 + (c*16 + m)*16 + q*8;
            o0.x = f2b(wp[0]); o0.y = f2b(wp[1]); o0.z = f2b(wp[2]); o0.w = f2b(wp[3]);
            o1.x = f2b(wp[4]); o1.y = f2b(wp[5]); o1.z = f2b(wp[6]); o1.w = f2b(wp[7]);
        }
        *(ushort4*)(gW + tid*8)     = o0;
        *(ushort4*)(gW + tid*8 + 4) = o1;
    }
    if (tid < 128){
        int lane = tid & 63, kb = tid >> 6;
        int q = lane >> 4, d = lane & 15;
        unsigned short uo[8];
#pragma unroll
        for (int j = 0; j < 8; j++){
            int w = kb*32 + q*8 + j;
            float u = p3[1024 + w*16 + d] * fast_sigmoid(p3[2048 + w*16 + d]);
            uo[j] = f2b(u);
        }
        *(ushort4*)(gU + tid*8)     = *(ushort4*)&uo[0];
        *(ushort4*)(gU + tid*8 + 4) = *(ushort4*)&uo[4];
    } else if (tid < 192){
        int w = tid - 128;
        g[1536 + w] = p3[3072 + w];
    } else {
        int w = tid - 192;
        float s = 0.f;
#pragma unroll
        for (int d = 0; d < 16; d++){
            float u = p3[1024 + w*16 + d] * fast_sigmoid(p3[2048 + w*16 + d]);
            s += p3[w*16 + d] * u;
        }
        g[1600 + w] = s;
        sred[w] = s;
    }
    __syncthreads();
    if (tid == 0){
        float st = 0.f;
#pragma unroll
        for (int w = 0; w < 64; w++) st += sred[w];
        g[1664] = st;
    }
}

// ===== single-block hyper (fallback only, OLD layout stride 2304) ==========
__global__ void k_hyper(const float* __restrict__ h1w, const float* __restrict__ h1b,
                        const float* __restrict__ h2w, const float* __restrict__ h2b,
                        const float* __restrict__ h3w, const float* __restrict__ h3b,
                        float* __restrict__ hyp){
    int sidx = blockIdx.x;
    float t = stage_t(sidx);
    __shared__ float p1[64], p2[64];
    __shared__ float p3[3136];
    int tid = threadIdx.x;
    if (tid < 64) p1[tid] = fast_tanh(t * h1w[tid] + h1b[tid]);
    __syncthreads();
    if (tid < 64){
        float a = h2b[tid];
#pragma unroll
        for (int k = 0; k < 64; k++) a += p1[k] * h2w[k*64 + tid];
        p2[tid] = fast_tanh(a);
    }
    __syncthreads();
    for (int m = tid; m < 3136; m += 256){
        float a = h3b[m];
#pragma unroll
        for (int k = 0; k < 64; k++) a += p2[k] * h3w[k*3136 + m];
        p3[m] = a;
    }
    __syncthreads();
    float* g = hyp + (size_t)sidx * 2304;
    for (int m = tid; m < 1024; m += 256){
        g[m] = p3[m];
        float u = p3[1024 + m] * fast_sigmoid(p3[2048 + m]);
        g[1024 + (m & 15)*64 + (m >> 4)] = u;
        p3[1024 + m] = u;
    }
    if (tid < 64) g[2048 + tid] = p3[3072 + tid];
    __syncthreads();
    if (tid < 64){
        float s = 0.f;
#pragma unroll
        for (int d = 0; d < 16; d++) s += p3[tid*16 + d] * p3[1024 + tid*16 + d];
        g[2112 + tid] = s;
    }
}

// ===== FUSED FALLBACK (round-3, proven) ====================================
template<int LOUT, int INW, int OUTW, int OUTOFF>
__device__ __forceinline__ void conv_gemm(const unsigned short* __restrict__ Wg,
                                          const float* __restrict__ bias,
                                          const unsigned short* inL,
                                          unsigned short* outL, int tid){
    constexpr int N  = LOUT * LOUT;
    constexpr int NT = (N + 15) / 16;
    const int lane  = tid & 63;
    const int wave  = tid >> 6;
    const int mtile = wave & 1;
    const int quad  = lane >> 4;
    const int nn    = lane & 15;
    bf16x8 afr[9];
    const unsigned short* wp = Wg + (mtile*16 + nn)*32 + quad*8;
#pragma unroll
    for (int s = 0; s < 9; s++)
        afr[s] = *(const bf16x8*)(wp + s*1024);
    float4 bco = *(const float4*)(bias + mtile*16 + quad*4);
    for (int t = (wave >> 1); t < NT; t += 2){
        int pos = t*16 + nn;
        int pc  = pos < N ? pos : N - 1;
        int y = pc / LOUT, x = pc - y*LOUT;
        const unsigned short* ib = inL + (y*INW + x)*32 + quad*8;
        f32x4 acc = {0.f, 0.f, 0.f, 0.f};
#pragma unroll
        for (int r = 0; r < 3; r++)
#pragma unroll
            for (int s = 0; s < 3; s++)
                acc = __builtin_amdgcn_mfma_f32_16x16x32_bf16(
                        afr[r*3+s], *(const bf16x8*)(ib + (r*INW + s)*32), acc, 0, 0, 0);
        if (pos < N){
            ushort4 o;
            o.x = f2b(fast_tanh(acc[0] + bco.x));
            o.y = f2b(fast_tanh(acc[1] + bco.y));
            o.z = f2b(fast_tanh(acc[2] + bco.z));
            o.w = f2b(fast_tanh(acc[3] + bco.w));
            int opix = y*OUTW + x + OUTOFF;
            *(ushort4*)(outL + opix*32 + mtile*16 + quad*4) = o;
        }
    }
}

__global__ void __launch_bounds__(256)
k_enc_f(const float* __restrict__ x,
        const float* __restrict__ c0w, const float* __restrict__ c0b,
        const unsigned short* __restrict__ wc1, const float* __restrict__ c1b,
        const unsigned short* __restrict__ wc2, const float* __restrict__ c2b,
        const float* __restrict__ elw, const float* __restrict__ elb,
        float* __restrict__ z1){
    __shared__ float X[784];
    __shared__ __align__(16) unsigned short H0[21632];
    __shared__ __align__(16) unsigned short H1[18432];
    __shared__ __align__(16) unsigned short H2[15488];
    __shared__ float red[16*17];
    const int tid = threadIdx.x, b = blockIdx.x;
    for (int i = tid; i < 784; i += 256) X[i] = x[b*784 + i];
    __syncthreads();
    for (int pos = tid; pos < 676; pos += 256){
        int y = pos / 26, xx = pos - y*26;
        float v[9];
#pragma unroll
        for (int r = 0; r < 3; r++)
#pragma unroll
            for (int s = 0; s < 3; s++)
                v[r*3+s] = X[(y+r)*28 + xx + s];
#pragma unroll
        for (int g = 0; g < 8; g++){
            float a0 = c0b[g*4+0], a1 = c0b[g*4+1], a2 = c0b[g*4+2], a3 = c0b[g*4+3];
#pragma unroll
            for (int k = 0; k < 9; k++){
                a0 += v[k] * c0w[(g*4+0)*9 + k];
                a1 += v[k] * c0w[(g*4+1)*9 + k];
                a2 += v[k] * c0w[(g*4+2)*9 + k];
                a3 += v[k] * c0w[(g*4+3)*9 + k];
            }
            ushort4 o;
            o.x = f2b(fast_tanh(a0)); o.y = f2b(fast_tanh(a1));
            o.z = f2b(fast_tanh(a2)); o.w = f2b(fast_tanh(a3));
            *(ushort4*)(H0 + pos*32 + g*4) = o;
        }
    }
    __syncthreads();
    conv_gemm<24, 26, 24, 0>(wc1, c1b, H0, H1, tid);
    __syncthreads();
    conv_gemm<22, 24, 22, 0>(wc2, c2b, H1, H2, tid);
    __syncthreads();
    {
        int fg = tid >> 4, l = tid & 15;
        float a = 0.f;
        for (int ci = 0; ci < 32; ci++)
            for (int pos = fg; pos < 484; pos += 16)
                a += b2f(H2[pos*32 + ci]) * elw[(ci*484 + pos)*16 + l];
        red[fg*17 + l] = a;
        __syncthreads();
        if (tid < 16){
            float s = elb[tid];
#pragma unroll
            for (int g = 0; g < 16; g++) s += red[g*17 + tid];
            z1[b*16 + tid] = s;
        }
    }
}

__global__ void __launch_bounds__(256)
k_dec_f(const float* __restrict__ z1,
        const float* __restrict__ dlw, const float* __restrict__ dlb,
        const unsigned short* __restrict__ wt0, const float* __restrict__ t0b,
        const unsigned short* __restrict__ wt1, const float* __restrict__ t1b,
        const float* __restrict__ t2w, const float* __restrict__ t2b,
        float* __restrict__ out){
    __shared__ __align__(16) unsigned short D0[21632];
    __shared__ __align__(16) unsigned short D1[25088];
    __shared__ __align__(16) unsigned short D2[28800];
    const int tid = threadIdx.x, b = blockIdx.x;
    {
        uint4 zq = {0,0,0,0};
        for (int i = tid; i < 2704; i += 256) ((uint4*)D0)[i] = zq;
        for (int i = tid; i < 3136; i += 256) ((uint4*)D1)[i] = zq;
        for (int i = tid; i < 3600; i += 256) ((uint4*)D2)[i] = zq;
    }
    float zz[16];
#pragma unroll
    for (int l = 0; l < 16; l++) zz[l] = z1[b*16 + l];
    __syncthreads();
    for (int f = tid; f < 15488; f += 256){
        float a = dlb[f];
#pragma unroll
        for (int l = 0; l < 16; l++) a += zz[l] * dlw[l*15488 + f];
        int ci = f / 484, pos = f - ci*484;
        int y = pos / 22, xx = pos - y*22;
        D0[((y+2)*26 + xx + 2)*32 + ci] = f2b(fast_tanh(a));
    }
    __syncthreads();
    conv_gemm<24, 26, 28, 58>(wt0, t0b, D0, D1, tid);
    __syncthreads();
    conv_gemm<26, 28, 30, 62>(wt1, t1b, D1, D2, tid);
    __syncthreads();
    for (int o = tid; o < 784; o += 256){
        int y = o / 28, xx = o - y*28;
        float a = t2b[0];
#pragma unroll
        for (int r = 0; r < 3; r++)
#pragma unroll
            for (int s = 0; s < 3; s++){
                const unsigned short* pp = D2 + ((y+r)*30 + xx + s)*32;
                int wi = (2-r)*3 + (2-s);
#pragma unroll
                for (int g = 0; g < 4; g++){
                    bf16x8 h = *(const bf16x8*)(pp + g*8);
#pragma unroll
                    for (int j = 0; j < 8; j++)
                        a += b2f((unsigned short)h[j]) * t2w[(g*8+j)*9 + wi];
                }
            }
        out[(size_t)b*784 + o] = a;
    }
}

// ===== CNF fallback (R7, old hyp layout) ===================================
struct PF { float4 Wr[4]; float4 Ur[4]; float Bb, sw; };
__device__ __forceinline__ void load_pf(const float* __restrict__ g,
                                        int lane, int q, int d, PF& p){
    const float4* w4 = (const float4*)(g + lane*16);
    p.Wr[0] = w4[0]; p.Wr[1] = w4[1]; p.Wr[2] = w4[2]; p.Wr[3] = w4[3];
    const float4* u4 = (const float4*)(g + 1024 + d*64 + q*16);
    p.Ur[0] = u4[0]; p.Ur[1] = u4[1]; p.Ur[2] = u4[2]; p.Ur[3] = u4[3];
    p.Bb = g[2048 + lane];
    p.sw = g[2112 + lane];
}
__global__ void __launch_bounds__(64)
k_cnf_f(const float* __restrict__ z1, const float* __restrict__ hyp,
        float* __restrict__ part){
    __shared__ __align__(16) float zsl[16];
    __shared__ __align__(16) float hhl[64];
    const int lane = threadIdx.x;
    const int q = lane >> 4, d = lane & 15;
    const float dt = -0.5f;
    float z  = z1[(size_t)blockIdx.x*16 + d];
    float zs = z;
    float lp = 0.f, zacc = 0.f, lacc = 0.f;
    if (lane < 16) zsl[lane] = zs;
    PF cur, nxt;
    load_pf(hyp, lane, q, d, cur);
    for (int sidx = 0; sidx < 80; sidx++){
        __syncthreads();
        if (sidx < 79) load_pf(hyp + (size_t)(sidx + 1)*2304, lane, q, d, nxt);
        const float4* zp = (const float4*)zsl;
        float4 z0 = zp[0], z1v = zp[1], z2 = zp[2], z3 = zp[3];
        float a = cur.Bb;
        a += z0.x*cur.Wr[0].x + z0.y*cur.Wr[0].y + z0.z*cur.Wr[0].z + z0.w*cur.Wr[0].w;
        a += z1v.x*cur.Wr[1].x + z1v.y*cur.Wr[1].y + z1v.z*cur.Wr[1].z + z1v.w*cur.Wr[1].w;
        a += z2.x*cur.Wr[2].x + z2.y*cur.Wr[2].y + z2.z*cur.Wr[2].z + z2.w*cur.Wr[2].w;
        a += z3.x*cur.Wr[3].x + z3.y*cur.Wr[3].y + z3.z*cur.Wr[3].z + z3.w*cur.Wr[3].w;
        float hh = fast_tanh(a);
        float e = (1.f - hh*hh) * cur.sw;
#pragma unroll
        for (int off = 1; off < 64; off <<= 1)
            e += __shfl_xor(e, off);
        hhl[lane] = hh;
        __syncthreads();
        const float4* hp = (const float4*)(hhl + q*16);
        float4 h0 = hp[0], h1 = hp[1], h2 = hp[2], h3 = hp[3];
        float dzp = 0.f;
        dzp += h0.x*cur.Ur[0].x + h0.y*cur.Ur[0].y + h0.z*cur.Ur[0].z + h0.w*cur.Ur[0].w;
        dzp += h1.x*cur.Ur[1].x + h1.y*cur.Ur[1].y + h1.z*cur.Ur[1].z + h1.w*cur.Ur[1].w;
        dzp += h2.x*cur.Ur[2].x + h2.y*cur.Ur[2].y + h2.z*cur.Ur[2].z + h2.w*cur.Ur[2].w;
        dzp += h3.x*cur.Ur[3].x + h3.y*cur.Ur[3].y + h3.z*cur.Ur[3].z + h3.w*cur.Ur[3].w;
        dzp += __shfl_xor(dzp, 16);
        dzp += __shfl_xor(dzp, 32);
        float dz = dzp * (1.f/64.f);
        float dl = -e  * (1.f/64.f);
        int st = sidx & 3;
        float wgt = (st == 0 || st == 3) ? 1.f : 2.f;
        zacc += wgt * dz;
        lacc += wgt * dl;
        if (st < 3){
            float aa = (st == 2) ? 1.0f : 0.5f;
            zs = z + aa * dt * dz;
        } else {
            z  += (dt/6.f) * zacc;
            lp += (dt/6.f) * lacc;
            zs = z;
            zacc = 0.f; lacc = 0.f;
        }
        if (lane < 16) zsl[lane] = zs;
        cur = nxt;
    }
    float sq = z * z;
#pragma unroll
    for (int off = 1; off < 16; off <<= 1) sq += __shfl_xor(sq, off, 16);
    float logp = -0.5f * (16.f*1.8378770664093453f + 16.f*(-2.302585092994046f) + sq*10.f);
    if (lane == 0) part[blockIdx.x] = logp - lp;
}

__global__ void k_final(const float* __restrict__ part, float* __restrict__ out){
    __shared__ float red[256];
    int tid = threadIdx.x;
    float s = 0.f;
#pragma unroll
    for (int k = 0; k < 8; k++) s += part[tid + k*256];
    red[tid] = s;
    __syncthreads();
    for (int st = 128; st > 0; st >>= 1){
        if (tid < st) red[tid] += red[tid + st];
        __syncthreads();
    }
    if (tid == 0) out[1605632] = red[0] * (1.f/2048.f);
}

extern "C" void kernel_launch(void* const* d_in, const int* in_sizes, int n_in,
                              void* d_out, int out_size, void* d_ws, size_t ws_size,
                              hipStream_t stream){
    const float* x   = (const float*)d_in[0];
    const float* c0w = (const float*)d_in[1];
    const float* c0b = (const float*)d_in[2];
    const float* c1w = (const float*)d_in[3];
    const float* c1b = (const float*)d_in[4];
    const float* c2w = (const float*)d_in[5];
    const float* c2b = (const float*)d_in[6];
    const float* elw = (const float*)d_in[7];
    const float* elb = (const float*)d_in[8];
    const float* dlw = (const float*)d_in[9];
    const float* dlb = (const float*)d_in[10];
    const float* t0w = (const float*)d_in[11];
    const float* t0b = (const float*)d_in[12];
    const float* t1w = (const float*)d_in[13];
    const float* t1b = (const float*)d_in[14];
    const float* t2w = (const float*)d_in[15];
    const float* t2b = (const float*)d_in[16];
    const float* h1w = (const float*)d_in[17];
    const float* h1b = (const float*)d_in[18];
    const float* h2w = (const float*)d_in[19];
    const float* h2b = (const float*)d_in[20];
    const float* h3w = (const float*)d_in[21];
    const float* h3b = (const float*)d_in[22];

    float* ws   = (float*)d_ws;
    float* z1   = ws;                          // 32768 f
    float* hyp  = z1 + 32768;                  // 184320 f (both layouts fit)
    float* part = hyp + 184320;                // 2048 f
    float* zmid = part + 2048;                 // 32768 f
    float* lpmid= zmid + 32768;                // 2048 f
    float* p2ws = lpmid + 2048;                // 5120 f
    float* p3ws = p2ws + 5120;                 // 256000 f
    float* dlbT = p3ws + 256000;               // 15488 f
    unsigned short* wc1  = (unsigned short*)(dlbT + 15488);   // 9216 each
    unsigned short* wc2  = wc1 + 9216;
    unsigned short* wt0  = wc2 + 9216;
    unsigned short* wt1  = wt0 + 9216;
    unsigned short* t2wPk = wt1 + 9216;        // 288
    unsigned short* elwT = t2wPk + 288;        // 247808
    unsigned short* dlwT = elwT + 247808;      // 247808
    unsigned short* act  = dlwT + 247808;      // byte offset 3,187,776
    float* rec  = (float*)d_out;

    // per-image global: X (25088 sh, A1/D1) + Y (15488 sh, A2/D0c) = 81152 B
    const size_t MISC = 3187776;
    int CH = 0;
    const int cands[6] = {2048, 1024, 512, 256, 128, 64};
    for (int c = 0; c < 6; c++){
        size_t need = MISC + (size_t)cands[c] * 81152;
        if (need <= ws_size){ CH = cands[c]; break; }
    }

    if (CH == 0){
        k_hyper<<<80, 256, 0, stream>>>(h1w, h1b, h2w, h2b, h3w, h3b, hyp);
        k_prep <<<64,   256, 0, stream>>>(c1w, c2w, t0w, t1w, elw, dlw, elb, dlb, t2w,
                                          wc1, wc2, wt0, wt1, t2wPk, wt1, wt1, z1, z1, 0);
        k_enc_f<<<2048, 256, 0, stream>>>(x, c0w, c0b, wc1, c1b, wc2, c2b, elw, elb, z1);
        k_cnf_f<<<2048,  64, 0, stream>>>(z1, hyp, part);
        k_dec_f<<<2048, 256, 0, stream>>>(z1, dlw, dlb, wt0, t0b, wt1, t1b, t2w, t2b, rec);
        k_final<<<1,    256, 0, stream>>>(part, rec);
        return;
    }

    k_hyp1<<<80,           64, 0, stream>>>(h1w, h1b, h2w, h2b, p2ws);
    k_hyp2<<<dim3(13,80), 256, 0, stream>>>(p2ws, h3w, h3b, p3ws);
    k_hyp3<<<80,          256, 0, stream>>>(p3ws, hyp);

    k_prep<<<64, 256, 0, stream>>>(c1w, c2w, t0w, t1w, elw, dlw, elb, dlb, t2w,
                                   wc1, wc2, wt0, wt1, t2wPk, elwT, dlwT, dlbT, z1, 1);

    unsigned short* X = act;                           // CH*25088: A1 / D1
    unsigned short* Y = X + (size_t)CH*25088;          // CH*15488: A2 / D0c

    for (int cb = 0; cb < Bsz; cb += CH){
        int last = (cb + CH >= Bsz);
        int nCnf = last ? 128 : 0;
        k_enc01<<<CH, 256, 0, stream>>>(x, c0w, c0b, wc1, c1b, X, cb);
        k_convM<24,22,22,0, 25088, 15488><<<(CH*31 + 15)/16, 256, 0, stream>>>(X, wc2, c2b, Y, CH);
        k_encg<<<dim3(CH/16, 4), 256, 0, stream>>>(Y, elwT, z1, cb, CH);
        k_decgM<<<dim3(61, CH/16), 256, 0, stream>>>(z1, dlwT, dlbT, Y, cb);
        k_dect0c<<<CH + nCnf, 256, 0, stream>>>(Y, wt0, t0b, X, z1, hyp, zmid, lpmid, nCnf);
        k_dect12<<<CH + nCnf, 256, 0, stream>>>(X, wt1, t1b, t2wPk, t2b, rec,
                                                zmid, lpmid, hyp, part, cb, nCnf);
    }
    k_final<<<1, 256, 0, stream>>>(part, rec);
}

// Round 17
// 543.071 us; speedup vs baseline: 1.0662x; 1.0662x over previous
//
#include <hip/hip_runtime.h>
#include <math.h>

#define Bsz 2048

using bf16x8 = __attribute__((ext_vector_type(8))) short;
using f32x4  = __attribute__((ext_vector_type(4))) float;

__device__ __forceinline__ float fast_tanh(float x){
    float e = __expf(2.0f * x);
    return 1.0f - 2.0f / (e + 1.0f);
}
__device__ __forceinline__ float fast_sigmoid(float x){
    return 1.0f / (1.0f + __expf(-x));
}
__device__ __forceinline__ unsigned short f2b(float f){
    union { float f; unsigned u; } v; v.f = f;
    unsigned r = v.u + 0x7FFFu + ((v.u >> 16) & 1u);
    return (unsigned short)(r >> 16);
}
__device__ __forceinline__ float b2f(unsigned short s){
    union { unsigned u; float f; } v; v.u = ((unsigned)s) << 16;
    return v.f;
}

__device__ __forceinline__ float stage_t(int sidx){
    int i  = sidx >> 2, st = sidx & 3;
    float t = 10.0f - 0.5f * (float)i;
    if (st == 1 || st == 2) t -= 0.25f;
    else if (st == 3)       t -= 0.5f;
    return t;
}

// ===== weight prep ==========================================================
__global__ void k_prep(const float* __restrict__ c1w, const float* __restrict__ c2w,
                       const float* __restrict__ t0w, const float* __restrict__ t1w,
                       const float* __restrict__ elw, const float* __restrict__ dlw,
                       const float* __restrict__ elb, const float* __restrict__ dlb,
                       const float* __restrict__ t2w,
                       unsigned short* __restrict__ wc1, unsigned short* __restrict__ wc2,
                       unsigned short* __restrict__ wt0, unsigned short* __restrict__ wt1,
                       unsigned short* __restrict__ t2wPk,
                       unsigned short* __restrict__ elwT, unsigned short* __restrict__ dlwT,
                       float* __restrict__ dlbT, float* __restrict__ z1, int full){
    int gsz = gridDim.x * 256;
    for (int i = blockIdx.x*256 + threadIdx.x; i < 9216; i += gsz){
        int ci = i & 31, co = (i >> 5) & 31, s = i >> 10;
        wc1[i] = f2b(c1w[(co*32 + ci)*9 + s]);
        wc2[i] = f2b(c2w[(co*32 + ci)*9 + s]);
        wt0[i] = f2b(t0w[(ci*32 + co)*9 + (8 - s)]);
        wt1[i] = f2b(t1w[(ci*32 + co)*9 + (8 - s)]);
    }
    if (!full) return;
    for (int i = blockIdx.x*256 + threadIdx.x; i < 288; i += gsz){
        int tap = i >> 5, ci = i & 31;
        int r = tap / 3, s = tap - r*3;
        t2wPk[i] = f2b(t2w[ci*9 + (2-r)*3 + (2-s)]);
    }
    for (int i = blockIdx.x*256 + threadIdx.x; i < 32768; i += gsz)
        z1[i] = elb[i & 15];
    for (int i = blockIdx.x*256 + threadIdx.x; i < 15488; i += gsz){
        int pos = i >> 5, ci = i & 31;
        dlbT[i] = dlb[ci*484 + pos];
    }
    for (int i = blockIdx.x*256 + threadIdx.x; i < 247808; i += gsz){
        int l = i / 15488, f2 = i - l*15488;
        int pos = f2 >> 5, ci = f2 & 31;
        elwT[i] = f2b(elw[(ci*484 + pos)*16 + l]);
    }
    for (int i = blockIdx.x*256 + threadIdx.x; i < 247808; i += gsz){
        int f2 = i >> 4, l = i & 15;
        int pos = f2 >> 5, ci = f2 & 31;
        dlwT[i] = f2b(dlw[l*15488 + ci*484 + pos]);
    }
}

// ===== fused conv0 (1->32, VALU, ->LDS) + conv1 (MFMA, LDS->A1 global) =====
__global__ void __launch_bounds__(256)
k_enc01(const float* __restrict__ x, const float* __restrict__ c0w,
        const float* __restrict__ c0b, const unsigned short* __restrict__ wc1,
        const float* __restrict__ c1b, unsigned short* __restrict__ A1,
        int cb){
    __shared__ __align__(16) unsigned short A0L[676*36];
    __shared__ float X[784];
    const int tid = threadIdx.x, b = blockIdx.x;
    const float* xin = x + (size_t)(cb + b)*784;

    for (int i = tid; i < 784; i += 256) X[i] = xin[i];
    __syncthreads();

    for (int pos = tid; pos < 676; pos += 256){
        int y = pos / 26, xx = pos - y*26;
        float v[9];
#pragma unroll
        for (int r = 0; r < 3; r++)
#pragma unroll
            for (int s = 0; s < 3; s++)
                v[r*3+s] = X[(y+r)*28 + xx + s];
        float acc[32];
#pragma unroll
        for (int co = 0; co < 32; co++) acc[co] = c0b[co];
#pragma unroll
        for (int k = 0; k < 9; k++)
#pragma unroll
            for (int co = 0; co < 32; co++)
                acc[co] += v[k] * c0w[co*9 + k];
        unsigned short* ob = A0L + pos*36;
#pragma unroll
        for (int g = 0; g < 8; g++){
            ushort4 o;
            o.x = f2b(fast_tanh(acc[g*4+0])); o.y = f2b(fast_tanh(acc[g*4+1]));
            o.z = f2b(fast_tanh(acc[g*4+2])); o.w = f2b(fast_tanh(acc[g*4+3]));
            *(ushort4*)(ob + g*4) = o;
        }
    }
    __syncthreads();

    const int wave = tid >> 6, lane = tid & 63;
    const int q = lane >> 4, nn = lane & 15;
    bf16x8 af[2][9];
#pragma unroll
    for (int mt = 0; mt < 2; mt++)
#pragma unroll
        for (int s = 0; s < 9; s++)
            af[mt][s] = *(const bf16x8*)(wc1 + s*1024 + (mt*16 + nn)*32 + q*8);
    float4 bc0 = *(const float4*)(c1b + q*4);
    float4 bc1 = *(const float4*)(c1b + 16 + q*4);
    unsigned short* outb = A1 + (size_t)b*25088;

    for (int t = wave; t < 36; t += 4){
        int pos = t*16 + nn;
        int oy = pos / 24, ox = pos - oy*24;
        const unsigned short* ib = A0L + (oy*26 + ox)*36 + q*8;
        f32x4 acc0 = {0.f,0.f,0.f,0.f}, acc1 = {0.f,0.f,0.f,0.f};
#pragma unroll
        for (int r = 0; r < 3; r++){
            bf16x8 b0 = *(const bf16x8*)(ib + (r*26 + 0)*36);
            bf16x8 b1 = *(const bf16x8*)(ib + (r*26 + 1)*36);
            bf16x8 b2 = *(const bf16x8*)(ib + (r*26 + 2)*36);
            acc0 = __builtin_amdgcn_mfma_f32_16x16x32_bf16(af[0][r*3+0], b0, acc0, 0,0,0);
            acc1 = __builtin_amdgcn_mfma_f32_16x16x32_bf16(af[1][r*3+0], b0, acc1, 0,0,0);
            acc0 = __builtin_amdgcn_mfma_f32_16x16x32_bf16(af[0][r*3+1], b1, acc0, 0,0,0);
            acc1 = __builtin_amdgcn_mfma_f32_16x16x32_bf16(af[1][r*3+1], b1, acc1, 0,0,0);
            acc0 = __builtin_amdgcn_mfma_f32_16x16x32_bf16(af[0][r*3+2], b2, acc0, 0,0,0);
            acc1 = __builtin_amdgcn_mfma_f32_16x16x32_bf16(af[1][r*3+2], b2, acc1, 0,0,0);
        }
        int opix = oy*24 + ox;
        ushort4 o0, o1;
        o0.x = f2b(fast_tanh(acc0[0] + bc0.x)); o0.y = f2b(fast_tanh(acc0[1] + bc0.y));
        o0.z = f2b(fast_tanh(acc0[2] + bc0.z)); o0.w = f2b(fast_tanh(acc0[3] + bc0.w));
        o1.x = f2b(fast_tanh(acc1[0] + bc1.x)); o1.y = f2b(fast_tanh(acc1[1] + bc1.y));
        o1.z = f2b(fast_tanh(acc1[2] + bc1.z)); o1.w = f2b(fast_tanh(acc1[3] + bc1.w));
        *(ushort4*)(outb + opix*32 + q*4)      = o0;
        *(ushort4*)(outb + opix*32 + 16 + q*4) = o1;
    }
}

// ===== MFMA conv layer global->global (conv2) ==============================
template<int IL, int OL, int OW, int OOFF, int INS, int OUTS>
__global__ void __launch_bounds__(256)
k_convM(const unsigned short* __restrict__ in, const unsigned short* __restrict__ wg,
        const float* __restrict__ bias, unsigned short* __restrict__ out, int CH){
    constexpr int N  = OL * OL;
    constexpr int NT = (N + 15) / 16;
    const int tid = threadIdx.x;
    const int wave = tid >> 6, lane = tid & 63;
    const int q = lane >> 4, nn = lane & 15;
    const int nw = gridDim.x * 4;

    bf16x8 af[2][9];
#pragma unroll
    for (int mt = 0; mt < 2; mt++)
#pragma unroll
        for (int s = 0; s < 9; s++)
            af[mt][s] = *(const bf16x8*)(wg + s*1024 + (mt*16 + nn)*32 + q*8);
    float4 bc0 = *(const float4*)(bias + q*4);
    float4 bc1 = *(const float4*)(bias + 16 + q*4);

    for (int t = blockIdx.x*4 + wave; t < CH*NT; t += nw){
        int img = t / NT, tt = t - img*NT;
        const unsigned short* inb = in + (size_t)img * INS;
        unsigned short* outb = out + (size_t)img * OUTS;
        int pos = tt*16 + nn;
        int pc  = pos < N ? pos : N - 1;
        int oy = pc / OL, ox = pc - oy*OL;
        const unsigned short* ib = inb + (oy*IL + ox)*32 + q*8;
        f32x4 acc0 = {0.f,0.f,0.f,0.f}, acc1 = {0.f,0.f,0.f,0.f};
#pragma unroll
        for (int r = 0; r < 3; r++){
            bf16x8 b0 = *(const bf16x8*)(ib + (r*IL + 0)*32);
            bf16x8 b1 = *(const bf16x8*)(ib + (r*IL + 1)*32);
            bf16x8 b2 = *(const bf16x8*)(ib + (r*IL + 2)*32);
            acc0 = __builtin_amdgcn_mfma_f32_16x16x32_bf16(af[0][r*3+0], b0, acc0, 0,0,0);
            acc1 = __builtin_amdgcn_mfma_f32_16x16x32_bf16(af[1][r*3+0], b0, acc1, 0,0,0);
            acc0 = __builtin_amdgcn_mfma_f32_16x16x32_bf16(af[0][r*3+1], b1, acc0, 0,0,0);
            acc1 = __builtin_amdgcn_mfma_f32_16x16x32_bf16(af[1][r*3+1], b1, acc1, 0,0,0);
            acc0 = __builtin_amdgcn_mfma_f32_16x16x32_bf16(af[0][r*3+2], b2, acc0, 0,0,0);
            acc1 = __builtin_amdgcn_mfma_f32_16x16x32_bf16(af[1][r*3+2], b2, acc1, 0,0,0);
        }
        if (pos < N){
            int opix = oy*OW + ox + OOFF;
            ushort4 o0, o1;
            o0.x = f2b(fast_tanh(acc0[0] + bc0.x)); o0.y = f2b(fast_tanh(acc0[1] + bc0.y));
            o0.z = f2b(fast_tanh(acc0[2] + bc0.z)); o0.w = f2b(fast_tanh(acc0[3] + bc0.w));
            o1.x = f2b(fast_tanh(acc1[0] + bc1.x)); o1.y = f2b(fast_tanh(acc1[1] + bc1.y));
            o1.z = f2b(fast_tanh(acc1[2] + bc1.z)); o1.w = f2b(fast_tanh(acc1[3] + bc1.w));
            *(ushort4*)(outb + opix*32 + q*4)      = o0;
            *(ushort4*)(outb + opix*32 + 16 + q*4) = o1;
        }
    }
}

// ===== encoder GEMM (A2 in Y, stride 15488) ================================
__global__ void __launch_bounds__(256)
k_encg(const unsigned short* __restrict__ A2, const unsigned short* __restrict__ elwT,
       float* __restrict__ z1, int cb, int CH){
    int wave = threadIdx.x >> 6, lane = threadIdx.x & 63;
    int q = lane >> 4, nn = lane & 15;
    int imgb = blockIdx.x*16;
    const unsigned short* ap = A2 + (size_t)(imgb + nn)*15488 + q*8;
    const unsigned short* bp = elwT + (size_t)nn*15488 + q*8;
    f32x4 acc = {0.f,0.f,0.f,0.f};
    int s0 = blockIdx.y*121;
#pragma unroll 2
    for (int s = s0 + wave; s < s0 + 121; s += 4){
        bf16x8 a = *(const bf16x8*)(ap + s*32);
        bf16x8 b = *(const bf16x8*)(bp + s*32);
        acc = __builtin_amdgcn_mfma_f32_16x16x32_bf16(a, b, acc, 0,0,0);
    }
    float* zp = z1 + (size_t)(cb + imgb)*16;
#pragma unroll
    for (int i = 0; i < 4; i++)
        atomicAdd(zp + (q*4 + i)*16 + nn, acc[i]);
}

// ===== decoder as batch GEMM ==============================================
__global__ void __launch_bounds__(256)
k_decgM(const float* __restrict__ z1, const unsigned short* __restrict__ dlwT,
        const float* __restrict__ dlbT, unsigned short* __restrict__ D0c, int cb){
    __shared__ float zb[16*17];
    const int tid = threadIdx.x;
    const int wave = tid >> 6, lane = tid & 63;
    const int q = lane >> 4, n = lane & 15;
    const int imgb = blockIdx.y*16;
    zb[(tid >> 4)*17 + (tid & 15)] = z1[(size_t)(cb + imgb + (tid >> 4))*16 + (tid & 15)];
    __syncthreads();

    bf16x8 zf;
    if (q < 2){
        unsigned short tmp[8];
#pragma unroll
        for (int j = 0; j < 8; j++) tmp[j] = f2b(zb[n*17 + q*8 + j]);
        zf = *(bf16x8*)tmp;
    } else {
        bf16x8 zz = {0,0,0,0,0,0,0,0}; zf = zz;
    }

#pragma unroll
    for (int ii = 0; ii < 4; ii++){
        int mt = blockIdx.x*16 + wave*4 + ii;
        if (mt >= 968) break;
        int mb = mt*16;
        bf16x8 afr;
        if (q < 2) afr = *(const bf16x8*)(dlwT + (size_t)(mb + n)*16 + q*8);
        else { bf16x8 zz = {0,0,0,0,0,0,0,0}; afr = zz; }
        f32x4 acc = {0.f,0.f,0.f,0.f};
        acc = __builtin_amdgcn_mfma_f32_16x16x32_bf16(afr, zf, acc, 0,0,0);
        float4 bias = *(const float4*)(dlbT + mb + q*4);
        ushort4 o;
        o.x = f2b(fast_tanh(acc[0] + bias.x));
        o.y = f2b(fast_tanh(acc[1] + bias.y));
        o.z = f2b(fast_tanh(acc[2] + bias.z));
        o.w = f2b(fast_tanh(acc[3] + bias.w));
        *(ushort4*)(D0c + (size_t)(imgb + n)*15488 + mb + q*4) = o;
    }
}

// ===== CNF body (device; single wave, full 80 stages, writes part) =========
struct PM {
    bf16x8 Wf[4];
    bf16x8 Uf[2];
    float4 Bbf[4];
    float4 sf[4];
    float stot;
};
__device__ __forceinline__ void loadPM(const float* __restrict__ g, int lane, int q, PM& p){
    const unsigned short* gW = (const unsigned short*)g;
    const unsigned short* gU = (const unsigned short*)(g + 1024);
#pragma unroll
    for (int c = 0; c < 4; c++)
        p.Wf[c] = *(const bf16x8*)(gW + (c*64 + lane)*8);
#pragma unroll
    for (int kb = 0; kb < 2; kb++)
        p.Uf[kb] = *(const bf16x8*)(gU + (kb*64 + lane)*8);
#pragma unroll
    for (int c = 0; c < 4; c++){
        p.Bbf[c] = *(const float4*)(g + 1536 + c*16 + q*4);
        p.sf[c]  = *(const float4*)(g + 1600 + c*16 + q*4);
    }
    p.stot = g[1664];
}

__device__ __forceinline__ void cnf_body(const float* __restrict__ z1,
                                         const float* __restrict__ hyp,
                                         float* __restrict__ part, int bid,
                                         unsigned short* zsb, unsigned short* hhT){
    const int lane = threadIdx.x;
    const int q = lane >> 4, d = lane & 15;
    const float dt = -0.5f;

    float z[4], zacc[4], lacc[4], lp[4];
#pragma unroll
    for (int i = 0; i < 4; i++){
        z[i] = z1[(size_t)(bid*16 + q*4 + i)*16 + d];
        zacc[i] = 0.f; lacc[i] = 0.f; lp[i] = 0.f;
        zsb[(q*4 + i)*24 + d] = f2b(z[i]);
    }
    PM pm0, pm1;
    loadPM(hyp, lane, q, pm0);

#pragma unroll 2
    for (int sidx = 0; sidx < 80; sidx++){
        PM& cur = (sidx & 1) ? pm1 : pm0;
        PM& nxt = (sidx & 1) ? pm0 : pm1;
        if (sidx < 79) loadPM(hyp + (size_t)(sidx + 1)*2048, lane, q, nxt);

        bf16x8 zb;
        if (q < 2) zb = *(const bf16x8*)(zsb + d*24 + q*8);
        else { bf16x8 zz2 = {0,0,0,0,0,0,0,0}; zb = zz2; }

        f32x4 h0 = {0,0,0,0}, h1 = {0,0,0,0}, h2 = {0,0,0,0}, h3 = {0,0,0,0};
        h0 = __builtin_amdgcn_mfma_f32_16x16x32_bf16(cur.Wf[0], zb, h0, 0,0,0);
        h1 = __builtin_amdgcn_mfma_f32_16x16x32_bf16(cur.Wf[1], zb, h1, 0,0,0);
        h2 = __builtin_amdgcn_mfma_f32_16x16x32_bf16(cur.Wf[2], zb, h2, 0,0,0);
        h3 = __builtin_amdgcn_mfma_f32_16x16x32_bf16(cur.Wf[3], zb, h3, 0,0,0);

        float partial = 0.f;
        f32x4 hc[4] = {h0, h1, h2, h3};
#pragma unroll
        for (int c = 0; c < 4; c++){
            ushort4 o;
            float t0 = fast_tanh(hc[c][0] + cur.Bbf[c].x);
            float t1 = fast_tanh(hc[c][1] + cur.Bbf[c].y);
            float t2 = fast_tanh(hc[c][2] + cur.Bbf[c].z);
            float t3 = fast_tanh(hc[c][3] + cur.Bbf[c].w);
            partial += t0*t0*cur.sf[c].x + t1*t1*cur.sf[c].y
                     + t2*t2*cur.sf[c].z + t3*t3*cur.sf[c].w;
            o.x = f2b(t0); o.y = f2b(t1); o.z = f2b(t2); o.w = f2b(t3);
            *(ushort4*)(hhT + d*72 + c*16 + q*4) = o;
        }
        partial += __shfl_xor(partial, 16);
        partial += __shfl_xor(partial, 32);
        float trFull = (cur.stot - partial) * (1.f/64.f);

        bf16x8 a20 = *(const bf16x8*)(hhT + d*72 + q*8);
        bf16x8 a21 = *(const bf16x8*)(hhT + d*72 + 32 + q*8);
        f32x4 dzac = {0,0,0,0};
        dzac = __builtin_amdgcn_mfma_f32_16x16x32_bf16(a20, cur.Uf[0], dzac, 0,0,0);
        dzac = __builtin_amdgcn_mfma_f32_16x16x32_bf16(a21, cur.Uf[1], dzac, 0,0,0);

        int st = sidx & 3;
        float wgt = (st == 0 || st == 3) ? 1.f : 2.f;
#pragma unroll
        for (int i = 0; i < 4; i++){
            float dz = dzac[i] * (1.f/64.f);
            float dl = -__shfl(trFull, q*4 + i);
            zacc[i] += wgt * dz;
            lacc[i] += wgt * dl;
            float zsv;
            if (st < 3){
                float aa = (st == 2) ? 1.0f : 0.5f;
                zsv = z[i] + aa * dt * dz;
            } else {
                z[i]  += (dt/6.f) * zacc[i];
                lp[i] += (dt/6.f) * lacc[i];
                zsv = z[i];
                zacc[i] = 0.f; lacc[i] = 0.f;
            }
            zsb[(q*4 + i)*24 + d] = f2b(zsv);
        }
    }
    float sq[4];
#pragma unroll
    for (int i = 0; i < 4; i++) sq[i] = z[i]*z[i];
#pragma unroll
    for (int off = 1; off < 16; off <<= 1){
#pragma unroll
        for (int i = 0; i < 4; i++) sq[i] += __shfl_xor(sq[i], off, 16);
    }
    if (d == 0){
#pragma unroll
        for (int i = 0; i < 4; i++){
            float logp = -0.5f * (16.f*1.8378770664093453f
                                 + 16.f*(-2.302585092994046f) + sq[i]*10.f);
            part[bid*16 + q*4 + i] = logp - lp[i];
        }
    }
}

// ===== convT0 + full CNF piggyback (CNF blocks FIRST) ======================
__global__ void __launch_bounds__(256)
k_dect0c(const unsigned short* __restrict__ D0c, const unsigned short* __restrict__ wt0,
         const float* __restrict__ t0b, unsigned short* __restrict__ D1,
         const float* __restrict__ z1, const float* __restrict__ hyp,
         float* __restrict__ part, int nCnf){
    __shared__ __align__(16) unsigned short D0L[676*36];
    __shared__ __align__(16) unsigned short zsbS[16*24];
    __shared__ __align__(16) unsigned short hhTS[16*72];
    const int tid = threadIdx.x;

    if (blockIdx.x < nCnf){
        if (tid >= 64) return;
        cnf_body(z1, hyp, part, blockIdx.x, zsbS, hhTS);
        return;
    }
    const int b = blockIdx.x - nCnf;
    unsigned short* d1b = D1 + (size_t)b*25088;
    {
        uint4 zq = {0,0,0,0};
        for (int p = tid; p < 676; p += 256){
            int y = p / 26, xx = p - y*26;
            if (y < 2 || y >= 24 || xx < 2 || xx >= 24){
                uint4* pt = (uint4*)(D0L + p*36);
                pt[0] = zq; pt[1] = zq; pt[2] = zq; pt[3] = zq;
            }
        }
        for (int p = tid; p < 784; p += 256){
            int y = p / 28, xx = p - y*28;
            if (y < 2 || y >= 26 || xx < 2 || xx >= 26){
                uint4* pt = (uint4*)(d1b + p*32);
                pt[0] = zq; pt[1] = zq; pt[2] = zq; pt[3] = zq;
            }
        }
    }
    {
        const uint4* src = (const uint4*)(D0c + (size_t)b*15488);
        for (int c = tid; c < 1936; c += 256){
            uint4 v = src[c];
            int pos = c >> 2, p8 = (c & 3)*8;
            int y = pos / 22, xx = pos - y*22;
            *(uint4*)(D0L + ((y+2)*26 + xx + 2)*36 + p8) = v;
        }
    }
    __syncthreads();

    const int wave = tid >> 6, lane = tid & 63;
    const int q = lane >> 4, nn = lane & 15;
    bf16x8 af[2][9];
#pragma unroll
    for (int mt = 0; mt < 2; mt++)
#pragma unroll
        for (int s = 0; s < 9; s++)
            af[mt][s] = *(const bf16x8*)(wt0 + s*1024 + (mt*16 + nn)*32 + q*8);
    float4 bc0 = *(const float4*)(t0b + q*4);
    float4 bc1 = *(const float4*)(t0b + 16 + q*4);

    for (int t = wave; t < 36; t += 4){
        int pos = t*16 + nn;
        int oy = pos / 24, ox = pos - oy*24;
        const unsigned short* ib = D0L + (oy*26 + ox)*36 + q*8;
        f32x4 acc0 = {0.f,0.f,0.f,0.f}, acc1 = {0.f,0.f,0.f,0.f};
#pragma unroll
        for (int r = 0; r < 3; r++){
            bf16x8 b0 = *(const bf16x8*)(ib + (r*26 + 0)*36);
            bf16x8 b1 = *(const bf16x8*)(ib + (r*26 + 1)*36);
            bf16x8 b2 = *(const bf16x8*)(ib + (r*26 + 2)*36);
            acc0 = __builtin_amdgcn_mfma_f32_16x16x32_bf16(af[0][r*3+0], b0, acc0, 0,0,0);
            acc1 = __builtin_amdgcn_mfma_f32_16x16x32_bf16(af[1][r*3+0], b0, acc1, 0,0,0);
            acc0 = __builtin_amdgcn_mfma_f32_16x16x32_bf16(af[0][r*3+1], b1, acc0, 0,0,0);
            acc1 = __builtin_amdgcn_mfma_f32_16x16x32_bf16(af[1][r*3+1], b1, acc1, 0,0,0);
            acc0 = __builtin_amdgcn_mfma_f32_16x16x32_bf16(af[0][r*3+2], b2, acc0, 0,0,0);
            acc1 = __builtin_amdgcn_mfma_f32_16x16x32_bf16(af[1][r*3+2], b2, acc1, 0,0,0);
        }
        int opix = oy*28 + ox + 58;
        ushort4 o0, o1;
        o0.x = f2b(fast_tanh(acc0[0] + bc0.x)); o0.y = f2b(fast_tanh(acc0[1] + bc0.y));
        o0.z = f2b(fast_tanh(acc0[2] + bc0.z)); o0.w = f2b(fast_tanh(acc0[3] + bc0.w));
        o1.x = f2b(fast_tanh(acc1[0] + bc1.x)); o1.y = f2b(fast_tanh(acc1[1] + bc1.y));
        o1.z = f2b(fast_tanh(acc1[2] + bc1.z)); o1.w = f2b(fast_tanh(acc1[3] + bc1.w));
        *(ushort4*)(d1b + opix*32 + q*4)      = o0;
        *(ushort4*)(d1b + opix*32 + 16 + q*4) = o1;
    }
}

// ===== convT1 (-> compact 26-map LDS) + convT2 (OOB-zero) + final block ====
__global__ void __launch_bounds__(256)
k_dect12(const unsigned short* __restrict__ D1, const unsigned short* __restrict__ wt1,
         const float* __restrict__ t1b, const unsigned short* __restrict__ t2wPk,
         const float* __restrict__ t2b, float* __restrict__ out,
         const float* __restrict__ part, int cb, int CH){
    __shared__ __align__(16) unsigned short D2L[676*36];   // compact 26x26, stride 36
    const int tid = threadIdx.x, b = blockIdx.x;
    if (b >= CH){
        // final reduction of part -> out[1605632]
        __shared__ float red[256];
        float s = 0.f;
#pragma unroll
        for (int k = 0; k < 8; k++) s += part[tid + k*256];
        red[tid] = s;
        __syncthreads();
        for (int st = 128; st > 0; st >>= 1){
            if (tid < st) red[tid] += red[tid + st];
            __syncthreads();
        }
        if (tid == 0) out[1605632] = red[0] * (1.f/2048.f);
        return;
    }
    const unsigned short* d1b = D1 + (size_t)b*25088;
    const int wave = tid >> 6, lane = tid & 63;
    const int q = lane >> 4, nn = lane & 15;

    {   // convT1: D1 (28-map global) -> D2L compact 26-map
        bf16x8 af[2][9];
#pragma unroll
        for (int mt = 0; mt < 2; mt++)
#pragma unroll
            for (int s = 0; s < 9; s++)
                af[mt][s] = *(const bf16x8*)(wt1 + s*1024 + (mt*16 + nn)*32 + q*8);
        float4 bc0 = *(const float4*)(t1b + q*4);
        float4 bc1 = *(const float4*)(t1b + 16 + q*4);

        for (int t = wave; t < 43; t += 4){
            int pos = t*16 + nn;
            int pc  = pos < 676 ? pos : 675;
            int oy = pc / 26, ox = pc - oy*26;
            const unsigned short* ib = d1b + (oy*28 + ox)*32 + q*8;
            f32x4 acc0 = {0.f,0.f,0.f,0.f}, acc1 = {0.f,0.f,0.f,0.f};
#pragma unroll
            for (int r = 0; r < 3; r++){
                bf16x8 b0 = *(const bf16x8*)(ib + (r*28 + 0)*32);
                bf16x8 b1 = *(const bf16x8*)(ib + (r*28 + 1)*32);
                bf16x8 b2 = *(const bf16x8*)(ib + (r*28 + 2)*32);
                acc0 = __builtin_amdgcn_mfma_f32_16x16x32_bf16(af[0][r*3+0], b0, acc0, 0,0,0);
                acc1 = __builtin_amdgcn_mfma_f32_16x16x32_bf16(af[1][r*3+0], b0, acc1, 0,0,0);
                acc0 = __builtin_amdgcn_mfma_f32_16x16x32_bf16(af[0][r*3+1], b1, acc0, 0,0,0);
                acc1 = __builtin_amdgcn_mfma_f32_16x16x32_bf16(af[1][r*3+1], b1, acc1, 0,0,0);
                acc0 = __builtin_amdgcn_mfma_f32_16x16x32_bf16(af[0][r*3+2], b2, acc0, 0,0,0);
                acc1 = __builtin_amdgcn_mfma_f32_16x16x32_bf16(af[1][r*3+2], b2, acc1, 0,0,0);
            }
            if (pos < 676){
                int opix = oy*26 + ox;
                ushort4 o0, o1;
                o0.x = f2b(fast_tanh(acc0[0] + bc0.x)); o0.y = f2b(fast_tanh(acc0[1] + bc0.y));
                o0.z = f2b(fast_tanh(acc0[2] + bc0.z)); o0.w = f2b(fast_tanh(acc0[3] + bc0.w));
                o1.x = f2b(fast_tanh(acc1[0] + bc1.x)); o1.y = f2b(fast_tanh(acc1[1] + bc1.y));
                o1.z = f2b(fast_tanh(acc1[2] + bc1.z)); o1.w = f2b(fast_tanh(acc1[3] + bc1.w));
                *(ushort4*)(D2L + opix*36 + q*4)      = o0;
                *(ushort4*)(D2L + opix*36 + 16 + q*4) = o1;
            }
        }
    }
    __syncthreads();

    {   // convT2: 49 tiles x 9 MFMA, per-lane OOB zero B-frags
        bf16x8 wf[9];
#pragma unroll
        for (int tap = 0; tap < 9; tap++)
            wf[tap] = *(const bf16x8*)(t2wPk + tap*32 + q*8);
        float t2b0 = t2b[0];
        const bf16x8 zvec = {0,0,0,0,0,0,0,0};
        for (int t = wave; t < 49; t += 4){
            int p = t*16 + nn;
            int y = p / 28, xx = p - y*28;
            f32x4 acc = {0.f,0.f,0.f,0.f};
#pragma unroll
            for (int r = 0; r < 3; r++){
                int iy = y + r - 2;
                bool okY = (unsigned)iy < 26u;
#pragma unroll
                for (int s = 0; s < 3; s++){
                    int ix = xx + s - 2;
                    bool ok = okY && ((unsigned)ix < 26u);
                    bf16x8 bv = ok ? *(const bf16x8*)(D2L + (iy*26 + ix)*36 + q*8)
                                   : zvec;
                    acc = __builtin_amdgcn_mfma_f32_16x16x32_bf16(wf[r*3+s], bv, acc, 0,0,0);
                }
            }
            if (q == 0)
                out[(size_t)(cb + b)*784 + p] = acc[0] + t2b0;
        }
    }
}

// ===== hypernetwork, parallel 3-kernel path ================================
__global__ void __launch_bounds__(64)
k_hyp1(const float* __restrict__ h1w, const float* __restrict__ h1b,
       const float* __restrict__ h2w, const float* __restrict__ h2b,
       float* __restrict__ p2ws){
    __shared__ float p1l[64];
    int sidx = blockIdx.x, tid = threadIdx.x;
    float t = stage_t(sidx);
    p1l[tid] = fast_tanh(t * h1w[tid] + h1b[tid]);
    __syncthreads();
    float a0 = h2b[tid], a1 = 0.f, a2 = 0.f, a3 = 0.f;
#pragma unroll
    for (int k = 0; k < 64; k += 4){
        a0 += p1l[k]   * h2w[(k)*64   + tid];
        a1 += p1l[k+1] * h2w[(k+1)*64 + tid];
        a2 += p1l[k+2] * h2w[(k+2)*64 + tid];
        a3 += p1l[k+3] * h2w[(k+3)*64 + tid];
    }
    p2ws[sidx*64 + tid] = fast_tanh((a0 + a1) + (a2 + a3));
}

__global__ void __launch_bounds__(256)
k_hyp2(const float* __restrict__ p2ws, const float* __restrict__ h3w,
       const float* __restrict__ h3b, float* __restrict__ p3ws){
    __shared__ float p2l[64];
    int sidx = blockIdx.y, tid = threadIdx.x;
    if (tid < 64) p2l[tid] = p2ws[sidx*64 + tid];
    __syncthreads();
    int m = blockIdx.x*256 + tid;
    if (m >= 3136) return;
    const float* hp = h3w + m;
    float a0 = h3b[m], a1 = 0.f, a2 = 0.f, a3 = 0.f;
#pragma unroll
    for (int k = 0; k < 64; k += 4){
        a0 += p2l[k]   * hp[(size_t)(k)*3136];
        a1 += p2l[k+1] * hp[(size_t)(k+1)*3136];
        a2 += p2l[k+2] * hp[(size_t)(k+2)*3136];
        a3 += p2l[k+3] * hp[(size_t)(k+3)*3136];
    }
    p3ws[(size_t)sidx*3200 + m] = (a0 + a1) + (a2 + a3);
}

__global__ void __launch_bounds__(256)
k_hyp3(const float* __restrict__ p3ws, float* __restrict__ hyp){
    __shared__ float sred[64];
    int sidx = blockIdx.x, tid = threadIdx.x;
    const float* p3 = p3ws + (size_t)sidx*3200;
    float* g = hyp + (size_t)sidx*2048;
    unsigned short* gW = (unsigned short*)g;
    unsigned short* gU = (unsigned short*)(g + 1024);
    {
        int lane = tid & 63, c = tid >> 6;
        int q = lane >> 4, m = lane & 15;
        ushort4 o0 = {0,0,0,0}, o1 = {0,0,0,0};
        if (q < 2){
            const float* wp = p3 + (c*16 + m)*16 + q*8;
            o0.x = f2b(wp[0]); o0.y = f2b(wp[1]); o0.z = f2b(wp[2]); o0.w = f2b(wp[3]);
            o1.x = f2b(wp[4]); o1.y = f2b(wp[5]); o1.z = f2b(wp[6]); o1.w = f2b(wp[7]);
        }
        *(ushort4*)(gW + tid*8)     = o0;
        *(ushort4*)(gW + tid*8 + 4) = o1;
    }
    if (tid < 128){
        int lane = tid & 63, kb = tid >> 6;
        int q = lane >> 4, d = lane & 15;
        unsigned short uo[8];
#pragma unroll
        for (int j = 0; j < 8; j++){
            int w = kb*32 + q*8 + j;
            float u = p3[1024 + w*16 + d] * fast_sigmoid(p3[2048 + w*16 + d]);
            uo[j] = f2b(u);
        }
        *(ushort4*)(gU + tid*8)     = *(ushort4*)&uo[0];
        *(ushort4*)(gU + tid*8 + 4) = *(ushort4*)&uo[4];
    } else if (tid < 192){
        int w = tid - 128;
        g[1536 + w] = p3[3072 + w];
    } else {
        int w = tid - 192;
        float s = 0.f;
#pragma unroll
        for (int d = 0; d < 16; d++){
            float u = p3[1024 + w*16 + d] * fast_sigmoid(p3[2048 + w*16 + d]);
            s += p3[w*16 + d] * u;
        }
        g[1600 + w] = s;
        sred[w] = s;
    }
    __syncthreads();
    if (tid == 0){
        float st = 0.f;
#pragma unroll
        for (int w = 0; w < 64; w++) st += sred[w];
        g[1664] = st;
    }
}

// ===== single-block hyper (fallback only, OLD layout stride 2304) ==========
__global__ void k_hyper(const float* __restrict__ h1w, const float* __restrict__ h1b,
                        const float* __restrict__ h2w, const float* __restrict__ h2b,
                        const float* __restrict__ h3w, const float* __restrict__ h3b,
                        float* __restrict__ hyp){
    int sidx = blockIdx.x;
    float t = stage_t(sidx);
    __shared__ float p1[64], p2[64];
    __shared__ float p3[3136];
    int tid = threadIdx.x;
    if (tid < 64) p1[tid] = fast_tanh(t * h1w[tid] + h1b[tid]);
    __syncthreads();
    if (tid < 64){
        float a = h2b[tid];
#pragma unroll
        for (int k = 0; k < 64; k++) a += p1[k] * h2w[k*64 + tid];
        p2[tid] = fast_tanh(a);
    }
    __syncthreads();
    for (int m = tid; m < 3136; m += 256){
        float a = h3b[m];
#pragma unroll
        for (int k = 0; k < 64; k++) a += p2[k] * h3w[k*3136 + m];
        p3[m] = a;
    }
    __syncthreads();
    float* g = hyp + (size_t)sidx * 2304;
    for (int m = tid; m < 1024; m += 256){
        g[m] = p3[m];
        float u = p3[1024 + m] * fast_sigmoid(p3[2048 + m]);
        g[1024 + (m & 15)*64 + (m >> 4)] = u;
        p3[1024 + m] = u;
    }
    if (tid < 64) g[2048 + tid] = p3[3072 + tid];
    __syncthreads();
    if (tid < 64){
        float s = 0.f;
#pragma unroll
        for (int d = 0; d < 16; d++) s += p3[tid*16 + d] * p3[1024 + tid*16 + d];
        g[2112 + tid] = s;
    }
}

// ===== FUSED FALLBACK (round-3, proven) ====================================
template<int LOUT, int INW, int OUTW, int OUTOFF>
__device__ __forceinline__ void conv_gemm(const unsigned short* __restrict__ Wg,
                                          const float* __restrict__ bias,
                                          const unsigned short* inL,
                                          unsigned short* outL, int tid){
    constexpr int N  = LOUT * LOUT;
    constexpr int NT = (N + 15) / 16;
    const int lane  = tid & 63;
    const int wave  = tid >> 6;
    const int mtile = wave & 1;
    const int quad  = lane >> 4;
    const int nn    = lane & 15;
    bf16x8 afr[9];
    const unsigned short* wp = Wg + (mtile*16 + nn)*32 + quad*8;
#pragma unroll
    for (int s = 0; s < 9; s++)
        afr[s] = *(const bf16x8*)(wp + s*1024);
    float4 bco = *(const float4*)(bias + mtile*16 + quad*4);
    for (int t = (wave >> 1); t < NT; t += 2){
        int pos = t*16 + nn;
        int pc  = pos < N ? pos : N - 1;
        int y = pc / LOUT, x = pc - y*LOUT;
        const unsigned short* ib = inL + (y*INW + x)*32 + quad*8;
        f32x4 acc = {0.f, 0.f, 0.f, 0.f};
#pragma unroll
        for (int r = 0; r < 3; r++)
#pragma unroll
            for (int s = 0; s < 3; s++)
                acc = __builtin_amdgcn_mfma_f32_16x16x32_bf16(
                        afr[r*3+s], *(const bf16x8*)(ib + (r*INW + s)*32), acc, 0, 0, 0);
        if (pos < N){
            ushort4 o;
            o.x = f2b(fast_tanh(acc[0] + bco.x));
            o.y = f2b(fast_tanh(acc[1] + bco.y));
            o.z = f2b(fast_tanh(acc[2] + bco.z));
            o.w = f2b(fast_tanh(acc[3] + bco.w));
            int opix = y*OUTW + x + OUTOFF;
            *(ushort4*)(outL + opix*32 + mtile*16 + quad*4) = o;
        }
    }
}

__global__ void __launch_bounds__(256)
k_enc_f(const float* __restrict__ x,
        const float* __restrict__ c0w, const float* __restrict__ c0b,
        const unsigned short* __restrict__ wc1, const float* __restrict__ c1b,
        const unsigned short* __restrict__ wc2, const float* __restrict__ c2b,
        const float* __restrict__ elw, const float* __restrict__ elb,
        float* __restrict__ z1){
    __shared__ float X[784];
    __shared__ __align__(16) unsigned short H0[21632];
    __shared__ __align__(16) unsigned short H1[18432];
    __shared__ __align__(16) unsigned short H2[15488];
    __shared__ float red[16*17];
    const int tid = threadIdx.x, b = blockIdx.x;
    for (int i = tid; i < 784; i += 256) X[i] = x[b*784 + i];
    __syncthreads();
    for (int pos = tid; pos < 676; pos += 256){
        int y = pos / 26, xx = pos - y*26;
        float v[9];
#pragma unroll
        for (int r = 0; r < 3; r++)
#pragma unroll
            for (int s = 0; s < 3; s++)
                v[r*3+s] = X[(y+r)*28 + xx + s];
#pragma unroll
        for (int g = 0; g < 8; g++){
            float a0 = c0b[g*4+0], a1 = c0b[g*4+1], a2 = c0b[g*4+2], a3 = c0b[g*4+3];
#pragma unroll
            for (int k = 0; k < 9; k++){
                a0 += v[k] * c0w[(g*4+0)*9 + k];
                a1 += v[k] * c0w[(g*4+1)*9 + k];
                a2 += v[k] * c0w[(g*4+2)*9 + k];
                a3 += v[k] * c0w[(g*4+3)*9 + k];
            }
            ushort4 o;
            o.x = f2b(fast_tanh(a0)); o.y = f2b(fast_tanh(a1));
            o.z = f2b(fast_tanh(a2)); o.w = f2b(fast_tanh(a3));
            *(ushort4*)(H0 + pos*32 + g*4) = o;
        }
    }
    __syncthreads();
    conv_gemm<24, 26, 24, 0>(wc1, c1b, H0, H1, tid);
    __syncthreads();
    conv_gemm<22, 24, 22, 0>(wc2, c2b, H1, H2, tid);
    __syncthreads();
    {
        int fg = tid >> 4, l = tid & 15;
        float a = 0.f;
        for (int ci = 0; ci < 32; ci++)
            for (int pos = fg; pos < 484; pos += 16)
                a += b2f(H2[pos*32 + ci]) * elw[(ci*484 + pos)*16 + l];
        red[fg*17 + l] = a;
        __syncthreads();
        if (tid < 16){
            float s = elb[tid];
#pragma unroll
            for (int g = 0; g < 16; g++) s += red[g*17 + tid];
            z1[b*16 + tid] = s;
        }
    }
}

__global__ void __launch_bounds__(256)
k_dec_f(const float* __restrict__ z1,
        const float* __restrict__ dlw, const float* __restrict__ dlb,
        const unsigned short* __restrict__ wt0, const float* __restrict__ t0b,
        const unsigned short* __restrict__ wt1, const float* __restrict__ t1b,
        const float* __restrict__ t2w, const float* __restrict__ t2b,
        float* __restrict__ out){
    __shared__ __align__(16) unsigned short D0[21632];
    __shared__ __align__(16) unsigned short D1[25088];
    __shared__ __align__(16) unsigned short D2[28800];
    const int tid = threadIdx.x, b = blockIdx.x;
    {
        uint4 zq = {0,0,0,0};
        for (int i = tid; i < 2704; i += 256) ((uint4*)D0)[i] = zq;
        for (int i = tid; i < 3136; i += 256) ((uint4*)D1)[i] = zq;
        for (int i = tid; i < 3600; i += 256) ((uint4*)D2)[i] = zq;
    }
    float zz[16];
#pragma unroll
    for (int l = 0; l < 16; l++) zz[l] = z1[b*16 + l];
    __syncthreads();
    for (int f = tid; f < 15488; f += 256){
        float a = dlb[f];
#pragma unroll
        for (int l = 0; l < 16; l++) a += zz[l] * dlw[l*15488 + f];
        int ci = f / 484, pos = f - ci*484;
        int y = pos / 22, xx = pos - y*22;
        D0[((y+2)*26 + xx + 2)*32 + ci] = f2b(fast_tanh(a));
    }
    __syncthreads();
    conv_gemm<24, 26, 28, 58>(wt0, t0b, D0, D1, tid);
    __syncthreads();
    conv_gemm<26, 28, 30, 62>(wt1, t1b, D1, D2, tid);
    __syncthreads();
    for (int o = tid; o < 784; o += 256){
        int y = o / 28, xx = o - y*28;
        float a = t2b[0];
#pragma unroll
        for (int r = 0; r < 3; r++)
#pragma unroll
            for (int s = 0; s < 3; s++){
                const unsigned short* pp = D2 + ((y+r)*30 + xx + s)*32;
                int wi = (2-r)*3 + (2-s);
#pragma unroll
                for (int g = 0; g < 4; g++){
                    bf16x8 h = *(const bf16x8*)(pp + g*8);
#pragma unroll
                    for (int j = 0; j < 8; j++)
                        a += b2f((unsigned short)h[j]) * t2w[(g*8+j)*9 + wi];
                }
            }
        out[(size_t)b*784 + o] = a;
    }
}

// ===== CNF fallback (R7, old hyp layout) ===================================
struct PF { float4 Wr[4]; float4 Ur[4]; float Bb, sw; };
__device__ __forceinline__ void load_pf(const float* __restrict__ g,
                                        int lane, int q, int d, PF& p){
    const float4* w4 = (const float4*)(g + lane*16);
    p.Wr[0] = w4[0]; p.Wr[1] = w4[1]; p.Wr[2] = w4[2]; p.Wr[3] = w4[3];
    const float4* u4 = (const float4*)(g + 1024 + d*64 + q*16);
    p.Ur[0] = u4[0]; p.Ur[1] = u4[1]; p.Ur[2] = u4[2]; p.Ur[3] = u4[3];
    p.Bb = g[2048 + lane];
    p.sw = g[2112 + lane];
}
__global__ void __launch_bounds__(64)
k_cnf_f(const float* __restrict__ z1, const float* __restrict__ hyp,
        float* __restrict__ part){
    __shared__ __align__(16) float zsl[16];
    __shared__ __align__(16) float hhl[64];
    const int lane = threadIdx.x;
    const int q = lane >> 4, d = lane & 15;
    const float dt = -0.5f;
    float z  = z1[(size_t)blockIdx.x*16 + d];
    float zs = z;
    float lp = 0.f, zacc = 0.f, lacc = 0.f;
    if (lane < 16) zsl[lane] = zs;
    PF cur, nxt;
    load_pf(hyp, lane, q, d, cur);
    for (int sidx = 0; sidx < 80; sidx++){
        __syncthreads();
        if (sidx < 79) load_pf(hyp + (size_t)(sidx + 1)*2304, lane, q, d, nxt);
        const float4* zp = (const float4*)zsl;
        float4 z0 = zp[0], z1v = zp[1], z2 = zp[2], z3 = zp[3];
        float a = cur.Bb;
        a += z0.x*cur.Wr[0].x + z0.y*cur.Wr[0].y + z0.z*cur.Wr[0].z + z0.w*cur.Wr[0].w;
        a += z1v.x*cur.Wr[1].x + z1v.y*cur.Wr[1].y + z1v.z*cur.Wr[1].z + z1v.w*cur.Wr[1].w;
        a += z2.x*cur.Wr[2].x + z2.y*cur.Wr[2].y + z2.z*cur.Wr[2].z + z2.w*cur.Wr[2].w;
        a += z3.x*cur.Wr[3].x + z3.y*cur.Wr[3].y + z3.z*cur.Wr[3].z + z3.w*cur.Wr[3].w;
        float hh = fast_tanh(a);
        float e = (1.f - hh*hh) * cur.sw;
#pragma unroll
        for (int off = 1; off < 64; off <<= 1)
            e += __shfl_xor(e, off);
        hhl[lane] = hh;
        __syncthreads();
        const float4* hp = (const float4*)(hhl + q*16);
        float4 h0 = hp[0], h1 = hp[1], h2 = hp[2], h3 = hp[3];
        float dzp = 0.f;
        dzp += h0.x*cur.Ur[0].x + h0.y*cur.Ur[0].y + h0.z*cur.Ur[0].z + h0.w*cur.Ur[0].w;
        dzp += h1.x*cur.Ur[1].x + h1.y*cur.Ur[1].y + h1.z*cur.Ur[1].z + h1.w*cur.Ur[1].w;
        dzp += h2.x*cur.Ur[2].x + h2.y*cur.Ur[2].y + h2.z*cur.Ur[2].z + h2.w*cur.Ur[2].w;
        dzp += h3.x*cur.Ur[3].x + h3.y*cur.Ur[3].y + h3.z*cur.Ur[3].z + h3.w*cur.Ur[3].w;
        dzp += __shfl_xor(dzp, 16);
        dzp += __shfl_xor(dzp, 32);
        float dz = dzp * (1.f/64.f);
        float dl = -e  * (1.f/64.f);
        int st = sidx & 3;
        float wgt = (st == 0 || st == 3) ? 1.f : 2.f;
        zacc += wgt * dz;
        lacc += wgt * dl;
        if (st < 3){
            float aa = (st == 2) ? 1.0f : 0.5f;
            zs = z + aa * dt * dz;
        } else {
            z  += (dt/6.f) * zacc;
            lp += (dt/6.f) * lacc;
            zs = z;
            zacc = 0.f; lacc = 0.f;
        }
        if (lane < 16) zsl[lane] = zs;
        cur = nxt;
    }
    float sq = z * z;
#pragma unroll
    for (int off = 1; off < 16; off <<= 1) sq += __shfl_xor(sq, off, 16);
    float logp = -0.5f * (16.f*1.8378770664093453f + 16.f*(-2.302585092994046f) + sq*10.f);
    if (lane == 0) part[blockIdx.x] = logp - lp;
}

__global__ void k_final(const float* __restrict__ part, float* __restrict__ out){
    __shared__ float red[256];
    int tid = threadIdx.x;
    float s = 0.f;
#pragma unroll
    for (int k = 0; k < 8; k++) s += part[tid + k*256];
    red[tid] = s;
    __syncthreads();
    for (int st = 128; st > 0; st >>= 1){
        if (tid < st) red[tid] += red[tid + st];
        __syncthreads();
    }
    if (tid == 0) out[1605632] = red[0] * (1.f/2048.f);
}

extern "C" void kernel_launch(void* const* d_in, const int* in_sizes, int n_in,
                              void* d_out, int out_size, void* d_ws, size_t ws_size,
                              hipStream_t stream){
    const float* x   = (const float*)d_in[0];
    const float* c0w = (const float*)d_in[1];
    const float* c0b = (const float*)d_in[2];
    const float* c1w = (const float*)d_in[3];
    const float* c1b = (const float*)d_in[4];
    const float* c2w = (const float*)d_in[5];
    const float* c2b = (const float*)d_in[6];
    const float* elw = (const float*)d_in[7];
    const float* elb = (const float*)d_in[8];
    const float* dlw = (const float*)d_in[9];
    const float* dlb = (const float*)d_in[10];
    const float* t0w = (const float*)d_in[11];
    const float* t0b = (const float*)d_in[12];
    const float* t1w = (const float*)d_in[13];
    const float* t1b = (const float*)d_in[14];
    const float* t2w = (const float*)d_in[15];
    const float* t2b = (const float*)d_in[16];
    const float* h1w = (const float*)d_in[17];
    const float* h1b = (const float*)d_in[18];
    const float* h2w = (const float*)d_in[19];
    const float* h2b = (const float*)d_in[20];
    const float* h3w = (const float*)d_in[21];
    const float* h3b = (const float*)d_in[22];

    float* ws   = (float*)d_ws;
    float* z1   = ws;                          // 32768 f
    float* hyp  = z1 + 32768;                  // 184320 f (both layouts fit)
    float* part = hyp + 184320;                // 2048 f
    float* zmid = part + 2048;                 // 32768 f (unused in fast path now)
    float* lpmid= zmid + 32768;                // 2048 f
    float* p2ws = lpmid + 2048;                // 5120 f
    float* p3ws = p2ws + 5120;                 // 256000 f
    float* dlbT = p3ws + 256000;               // 15488 f
    unsigned short* wc1  = (unsigned short*)(dlbT + 15488);   // 9216 each
    unsigned short* wc2  = wc1 + 9216;
    unsigned short* wt0  = wc2 + 9216;
    unsigned short* wt1  = wt0 + 9216;
    unsigned short* t2wPk = wt1 + 9216;        // 288
    unsigned short* elwT = t2wPk + 288;        // 247808
    unsigned short* dlwT = elwT + 247808;      // 247808
    unsigned short* act  = dlwT + 247808;      // byte offset 3,187,776
    float* rec  = (float*)d_out;

    // per-image global: X (25088 sh, A1/D1) + Y (15488 sh, A2/D0c) = 81152 B
    const size_t MISC = 3187776;
    int CH = 0;
    const int cands[6] = {2048, 1024, 512, 256, 128, 64};
    for (int c = 0; c < 6; c++){
        size_t need = MISC + (size_t)cands[c] * 81152;
        if (need <= ws_size){ CH = cands[c]; break; }
    }

    if (CH == 0){
        k_hyper<<<80, 256, 0, stream>>>(h1w, h1b, h2w, h2b, h3w, h3b, hyp);
        k_prep <<<64,   256, 0, stream>>>(c1w, c2w, t0w, t1w, elw, dlw, elb, dlb, t2w,
                                          wc1, wc2, wt0, wt1, t2wPk, wt1, wt1, z1, z1, 0);
        k_enc_f<<<2048, 256, 0, stream>>>(x, c0w, c0b, wc1, c1b, wc2, c2b, elw, elb, z1);
        k_cnf_f<<<2048,  64, 0, stream>>>(z1, hyp, part);
        k_dec_f<<<2048, 256, 0, stream>>>(z1, dlw, dlb, wt0, t0b, wt1, t1b, t2w, t2b, rec);
        k_final<<<1,    256, 0, stream>>>(part, rec);
        return;
    }

    k_hyp1<<<80,           64, 0, stream>>>(h1w, h1b, h2w, h2b, p2ws);
    k_hyp2<<<dim3(13,80), 256, 0, stream>>>(p2ws, h3w, h3b, p3ws);
    k_hyp3<<<80,          256, 0, stream>>>(p3ws, hyp);

    k_prep<<<64, 256, 0, stream>>>(c1w, c2w, t0w, t1w, elw, dlw, elb, dlb, t2w,
                                   wc1, wc2, wt0, wt1, t2wPk, elwT, dlwT, dlbT, z1, 1);

    unsigned short* X = act;                           // CH*25088: A1 / D1
    unsigned short* Y = X + (size_t)CH*25088;          // CH*15488: A2 / D0c

    for (int cb = 0; cb < Bsz; cb += CH){
        int last = (cb + CH >= Bsz);
        int nCnf = last ? 128 : 0;
        k_enc01<<<CH, 256, 0, stream>>>(x, c0w, c0b, wc1, c1b, X, cb);
        k_convM<24,22,22,0, 25088, 15488><<<(CH*31 + 15)/16, 256, 0, stream>>>(X, wc2, c2b, Y, CH);
        k_encg<<<dim3(CH/16, 4), 256, 0, stream>>>(Y, elwT, z1, cb, CH);
        k_decgM<<<dim3(61, CH/16), 256, 0, stream>>>(z1, dlwT, dlbT, Y, cb);
        k_dect0c<<<CH + nCnf, 256, 0, stream>>>(Y, wt0, t0b, X, z1, hyp, part, nCnf);
        k_dect12<<<CH + (last ? 1 : 0), 256, 0, stream>>>(X, wt1, t1b, t2wPk, t2b, rec,
                                                          part, cb, CH);
    }
}